// Round 1
// baseline (2379.732 us; speedup 1.0000x reference)
//
#include <hip/hip_runtime.h>
#include <math.h>

// ---------------- problem constants ----------------
#define NS 612          // states
#define NT 305          // transition params
#define NECOL 216       // emission cols
#define BATCH 32
#define TLEN 2048

// ---------------- ws layout (float offsets) ----------------
#define O_LVAL 0                    // [612*3] f32 light edge values (A after softmax)
#define O_LSRC 1836                 // [612*3] i32 light edge source states (612 = dummy)
#define O_G    3672                 // [101] f32: G[d] = exp(1 - wk^(d+1)), d=1..100
#define O_IZ3  3773                 // [101] f32: 1/Z3[j]
#define O_WD   3874                 // [1] i32: exact-window length W
#define O_PI   3875                 // [612] f32 softmax(init)
#define O_ET   4487                 // [216*612] f32 E^T (row = obs symbol, col = state)
// total floats = 4487 + 132192 = 136679  (~547 KB)

#define CE 2.7182818284590452f

// non-match-state ordinal -> state id
__device__ __forceinline__ int invord(int o) {
  if (o < 7) return o;
  if (o < 207) { int op = o - 7; return 8 + 3 * (op >> 1) + (op & 1); }
  return o + 100;
}

// ---------------- prep: transition-derived tables ----------------
__global__ void k_prep(const float* __restrict__ w, float* __restrict__ ws) {
  __shared__ float Gs[101], Z3[101], Z310[101];
  int tid = threadIdx.x;
  float wk = w[304];

  if (tid >= 1 && tid <= 100) {
    float p = wk;
    for (int k = 0; k < tid; ++k) p *= wk;     // wk^(tid+1)
    float g = expf(1.f - p);
    Gs[tid] = g;
    ws[O_G + tid] = g;
  }
  if (tid == 0) {
    Gs[0] = 0.f; ws[O_G] = 0.f;
    float a = fabsf(wk);
    int W = 100; float p = a * a * a;           // |wk|^(W+2) at W=1
    for (int W1 = 1; W1 <= 100; ++W1) {
      if (p < 1e-8f) { W = W1; break; }
      p *= a;
    }
    ((int*)ws)[O_WD] = W;
  }
  __syncthreads();
  if (tid <= 100) {
    // row 3+3j softmax denominator
    float z = expf(w[tid < 100 ? 1 + tid : 202]) + expf(w[101 + tid]);
    for (int d = 1; d <= 100 - tid; ++d) z += Gs[d];
    Z3[tid] = z;
    ws[O_IZ3 + tid] = 1.f / z;
    // row off+2+3i denominator
    Z310[tid] = expf(w[203 + tid]) + expf(1.f - w[203 + tid]);
  }
  __syncthreads();

  for (int s = tid; s < NS; s += 512) {
    int sr0 = NS, sr1 = NS, sr2 = NS;
    float v0 = 0.f, v1 = 0.f, v2 = 0.f;
    if (s == 0) {
      float Z0 = expf(1.f - w[0]) + expf(w[0]);
      sr0 = 0; v0 = expf(1.f - w[0]) / Z0;
    } else if (s == 1) {
      float Z0 = expf(1.f - w[0]) + expf(w[0]);
      sr0 = 0; v0 = expf(w[0]) / Z0;
    } else if (s == 2) { sr0 = 1; v0 = 1.f; }
    else if (s == 3)   { sr0 = 2; v0 = 1.f; }
    else if (s == 307) { sr0 = 306; v0 = 1.f; sr1 = 307; v1 = 0.5f; }
    else if (s == 611) { sr0 = 307; v0 = 0.5f; sr1 = 611; v1 = 1.f; }
    else if (s >= 4 && s <= 306 && (s - 4) % 3 == 0) {       // match col 4+3j
      int j = (s - 4) / 3;
      sr0 = 3 + 3 * j;   v0 = expf(w[j < 100 ? 1 + j : 202]) / Z3[j];
      sr1 = 310 + 3 * j; v1 = expf(w[203 + j]) / Z310[j];
    } else if (s >= 5 && s <= 305 && (s - 5) % 3 == 0) {
      int j = (s - 5) / 3; sr0 = 4 + 3 * j; v0 = 1.f;
    } else if (s >= 6 && s <= 306 && (s - 6) % 3 == 0) {
      int j = (s - 6) / 3; sr0 = 5 + 3 * j; v0 = 1.f;
    } else if (s >= 308 && s <= 608 && (s - 308) % 3 == 0) { // insert entry off+3i
      int i = (s - 308) / 3;
      sr0 = 3 + 3 * i;   v0 = expf(w[101 + i]) / Z3[i];
      sr1 = 310 + 3 * i; v1 = expf(1.f - w[203 + i]) / Z310[i];
    } else if (s >= 309 && s <= 609 && (s - 309) % 3 == 0) {
      int i = (s - 309) / 3; sr0 = 308 + 3 * i; v0 = 1.f;
    } else if (s >= 310 && s <= 610 && (s - 310) % 3 == 0) {
      int i = (s - 310) / 3; sr0 = 309 + 3 * i; v0 = 1.f;
    }
    ws[O_LVAL + s * 3 + 0] = v0;
    ws[O_LVAL + s * 3 + 1] = v1;
    ws[O_LVAL + s * 3 + 2] = v2;
    ((int*)ws)[O_LSRC + s * 3 + 0] = sr0;
    ((int*)ws)[O_LSRC + s * 3 + 1] = sr1;
    ((int*)ws)[O_LSRC + s * 3 + 2] = sr2;
  }
}

// ---------------- emission softmax -> E^T ----------------
__global__ void k_et(const float* __restrict__ ek, float* __restrict__ Et) {
  int s = blockIdx.x;
  int lane = threadIdx.x;      // 64 threads
  float x[4];
  float m = -1e30f;
  #pragma unroll
  for (int k = 0; k < 4; ++k) {
    int c = lane + 64 * k;
    x[k] = (c < NECOL) ? ek[s * NECOL + c] : -1e30f;
    m = fmaxf(m, x[k]);
  }
  #pragma unroll
  for (int o = 32; o; o >>= 1) m = fmaxf(m, __shfl_xor(m, o, 64));
  float e[4]; float sum = 0.f;
  #pragma unroll
  for (int k = 0; k < 4; ++k) {
    int c = lane + 64 * k;
    e[k] = (c < NECOL) ? expf(x[k] - m) : 0.f;
    sum += e[k];
  }
  #pragma unroll
  for (int o = 32; o; o >>= 1) sum += __shfl_xor(sum, o, 64);
  float inv = 1.f / sum;
  #pragma unroll
  for (int k = 0; k < 4; ++k) {
    int c = lane + 64 * k;
    if (c < NECOL) Et[c * NS + s] = e[k] * inv;
  }
}

// ---------------- init softmax ----------------
__global__ void k_pi(const float* __restrict__ ik, float* __restrict__ pi) {
  __shared__ float wm[10], wsm[10];
  int tid = threadIdx.x;       // 640 threads
  int lane = tid & 63, wid = tid >> 6;
  float x = (tid < NS) ? ik[tid] : -1e30f;
  float m = x;
  #pragma unroll
  for (int o = 32; o; o >>= 1) m = fmaxf(m, __shfl_xor(m, o, 64));
  if (lane == 0) wm[wid] = m;
  __syncthreads();
  float mm = wm[0];
  #pragma unroll
  for (int k = 1; k < 10; ++k) mm = fmaxf(mm, wm[k]);
  float e = (tid < NS) ? expf(x - mm) : 0.f;
  float sacc = e;
  #pragma unroll
  for (int o = 32; o; o >>= 1) sacc += __shfl_xor(sacc, o, 64);
  if (lane == 0) wsm[wid] = sacc;
  __syncthreads();
  float ss = 0.f;
  #pragma unroll
  for (int k = 0; k < 10; ++k) ss += wsm[k];
  if (tid < NS) pi[tid] = e / ss;
}

// ---------------- main forward scan: one block per sequence ----------------
__global__ __launch_bounds__(512) void k_main(const int* __restrict__ ids,
                                              const float* __restrict__ ws,
                                              float* __restrict__ out) {
  const float* lval  = ws + O_LVAL;
  const int*   lsrc  = (const int*)(ws + O_LSRC);
  const float* Gg    = ws + O_G;
  const float* iz3   = ws + O_IZ3;
  const int*   pWd   = (const int*)(ws + O_WD);
  const float* pi    = ws + O_PI;
  const float* Et    = ws + O_ET;

  __shared__ float alpha[616];
  __shared__ float etl[616];
  __shared__ float mdl[204];   // [0..100]=0 pad, data at [101..200]
  __shared__ float Pxl[204];   // same layout (wave-local inclusive scan)
  __shared__ float Gl[104];
  __shared__ float wred[8];
  __shared__ float tot0l;

  int tid = threadIdx.x, b = blockIdx.x;
  int lane = tid & 63, wid = tid >> 6;
  const int* idsb = ids + b * TLEN;

  // thread -> owned states (match col 4+3t owned by thread t for t in 1..100)
  int s0, s1;
  bool isMatch = (tid >= 1 && tid <= 100);
  if (isMatch) { s0 = 4 + 3 * tid; s1 = -1; }
  else {
    int q = (tid == 0) ? 0 : tid - 100;
    s0 = invord(q);
    s1 = (q < 100) ? q + 512 : -1;
  }

  int Wd = *pWd;
  float iz = (tid < 100) ? iz3[tid] : 0.f;

  // one-time LDS setup
  if (tid < 101) Gl[tid] = Gg[tid];
  if (tid >= 101 && tid < 104) Gl[tid] = 0.f;
  if (tid < 204) { mdl[tid] = 0.f; Pxl[tid] = 0.f; }
  if (tid < 4) alpha[612 + tid] = 0.f;

  // light edge tables into registers
  float lv0[3], lv1[3]; int ls0[3], ls1[3];
  #pragma unroll
  for (int k = 0; k < 3; ++k) {
    lv0[k] = lval[s0 * 3 + k];
    ls0[k] = lsrc[s0 * 3 + k];
    if (s1 >= 0) { lv1[k] = lval[s1 * 3 + k]; ls1[k] = lsrc[s1 * 3 + k]; }
    else         { lv1[k] = 0.f; ls1[k] = NS; }
  }

  // t = 0 init: alpha = pi * Et[obs0]
  int ob0 = idsb[0];
  float a0 = pi[s0] * Et[ob0 * NS + s0];
  float a1 = (s1 >= 0) ? pi[s1] * Et[ob0 * NS + s1] : 0.f;
  alpha[s0] = a0;
  if (s1 >= 0) alpha[s1] = a1;
  int obn = idsb[1];
  double ll = 0.0;
  __syncthreads();

  for (int t = 1; t < TLEN; ++t) {
    int ob = obn;
    obn = idsb[t < TLEN - 1 ? t + 1 : TLEN - 1];

    // ---- phase 1: all reads of alpha; stage Et row; lagged sum ----
    etl[tid] = Et[ob * NS + tid];
    if (tid < 100) etl[tid + 512] = Et[ob * NS + tid + 512];

    float p = a0 + a1;                       // previous-step alpha sum (lagged norm)
    #pragma unroll
    for (int o = 32; o; o >>= 1) p += __shfl_xor(p, o, 64);
    if (lane == 0) wred[wid] = p;

    float la0 = lv0[0] * alpha[ls0[0]] + lv0[1] * alpha[ls0[1]] + lv0[2] * alpha[ls0[2]];
    float la1 = lv1[0] * alpha[ls1[0]] + lv1[1] * alpha[ls1[1]] + lv1[2] * alpha[ls1[2]];

    if (tid < 100) {
      float md = alpha[3 + 3 * tid] * iz;
      mdl[101 + tid] = md;
      float x = md;
      #pragma unroll
      for (int o = 1; o < 64; o <<= 1) {
        float y = __shfl_up(x, o, 64);
        if (lane >= o) x += y;
      }
      Pxl[101 + tid] = x;                    // wave-local inclusive prefix
      if (tid == 63) tot0l = x;
    }
    __syncthreads();

    // ---- phase 2: combine, emission, lagged normalize, write alpha ----
    float s = 0.f;
    #pragma unroll
    for (int k = 0; k < 8; ++k) s += wred[k];
    float inv = 1.0f / s;
    ll += (double)logf(s);

    float dacc = 0.f;
    if (isMatch) {
      int j = tid;
      for (int d = 1; d <= Wd; ++d) dacc += mdl[101 + j - d] * Gl[d];
      int kk = j - Wd - 1;
      float lead = Pxl[101 + kk];            // zero-padded for kk<0
      if (kk >= 64) lead += tot0l;
      dacc += CE * lead;
    }
    a0 = (la0 + dacc) * etl[s0] * inv;
    alpha[s0] = a0;
    if (s1 >= 0) { a1 = la1 * etl[s1] * inv; alpha[s1] = a1; }
    else a1 = 0.f;
    __syncthreads();
  }

  // final: ll += log(sum(alpha_final))
  float p = a0 + a1;
  #pragma unroll
  for (int o = 32; o; o >>= 1) p += __shfl_xor(p, o, 64);
  if (lane == 0) wred[wid] = p;
  __syncthreads();
  float s = 0.f;
  #pragma unroll
  for (int k = 0; k < 8; ++k) s += wred[k];
  ll += (double)logf(s);
  if (tid == 0) out[b] = (float)ll;
}

// ---------------- launcher ----------------
extern "C" void kernel_launch(void* const* d_in, const int* in_sizes, int n_in,
                              void* d_out, int out_size, void* d_ws, size_t ws_size,
                              hipStream_t stream) {
  const int*   ids = (const int*)d_in[0];
  const float* w   = (const float*)d_in[1];
  const float* ek  = (const float*)d_in[2];
  const float* ik  = (const float*)d_in[3];
  float* ws  = (float*)d_ws;
  float* out = (float*)d_out;

  k_prep<<<1, 512, 0, stream>>>(w, ws);
  k_pi  <<<1, 640, 0, stream>>>(ik, ws + O_PI);
  k_et  <<<NS, 64, 0, stream>>>(ek, ws + O_ET);
  k_main<<<BATCH, 512, 0, stream>>>(ids, ws, out);
}

// Round 2
// 1531.330 us; speedup vs baseline: 1.5540x; 1.5540x over previous
//
#include <hip/hip_runtime.h>
#include <math.h>

// ---------------- problem constants ----------------
#define NS 612          // states
#define NECOL 216       // emission cols
#define BATCH 32
#define TLEN 2048

// ---------------- ws layout (float offsets) ----------------
#define O_LVAL 0                    // [612*3] f32 light edge values (A after softmax)
#define O_LSRC 1836                 // [612*3] i32 light edge source states (612 = dummy)
#define O_G    3672                 // [101] f32: G[d] = exp(1 - wk^(d+1)), d=1..100
#define O_IZ3  3773                 // [101] f32: 1/Z3[j]
#define O_WD   3874                 // [1] i32: exact-window length W
#define O_PI   3875                 // [612] f32 softmax(init)
#define O_ET   4487                 // [216*612] f32 E^T (row = obs symbol, col = state)

#define CE 2.7182818284590452f

// ---------------- prep: transition-derived tables (unchanged, verified) ------
__global__ void k_prep(const float* __restrict__ w, float* __restrict__ ws) {
  __shared__ float Gs[101], Z3[101], Z310[101];
  int tid = threadIdx.x;
  float wk = w[304];

  if (tid >= 1 && tid <= 100) {
    float p = wk;
    for (int k = 0; k < tid; ++k) p *= wk;     // wk^(tid+1)
    float g = expf(1.f - p);
    Gs[tid] = g;
    ws[O_G + tid] = g;
  }
  if (tid == 0) {
    Gs[0] = 0.f; ws[O_G] = 0.f;
    float a = fabsf(wk);
    int W = 100; float p = a * a * a;
    for (int W1 = 1; W1 <= 100; ++W1) {
      if (p < 1e-8f) { W = W1; break; }
      p *= a;
    }
    ((int*)ws)[O_WD] = W;
  }
  __syncthreads();
  if (tid <= 100) {
    float z = expf(w[tid < 100 ? 1 + tid : 202]) + expf(w[101 + tid]);
    for (int d = 1; d <= 100 - tid; ++d) z += Gs[d];
    Z3[tid] = z;
    ws[O_IZ3 + tid] = 1.f / z;
    Z310[tid] = expf(w[203 + tid]) + expf(1.f - w[203 + tid]);
  }
  __syncthreads();

  for (int s = tid; s < NS; s += 512) {
    int sr0 = NS, sr1 = NS, sr2 = NS;
    float v0 = 0.f, v1 = 0.f, v2 = 0.f;
    if (s == 0) {
      float Z0 = expf(1.f - w[0]) + expf(w[0]);
      sr0 = 0; v0 = expf(1.f - w[0]) / Z0;
    } else if (s == 1) {
      float Z0 = expf(1.f - w[0]) + expf(w[0]);
      sr0 = 0; v0 = expf(w[0]) / Z0;
    } else if (s == 2) { sr0 = 1; v0 = 1.f; }
    else if (s == 3)   { sr0 = 2; v0 = 1.f; }
    else if (s == 307) { sr0 = 306; v0 = 1.f; sr1 = 307; v1 = 0.5f; }
    else if (s == 611) { sr0 = 307; v0 = 0.5f; sr1 = 611; v1 = 1.f; }
    else if (s >= 4 && s <= 306 && (s - 4) % 3 == 0) {       // match col 4+3j
      int j = (s - 4) / 3;
      sr0 = 3 + 3 * j;   v0 = expf(w[j < 100 ? 1 + j : 202]) / Z3[j];
      sr1 = 310 + 3 * j; v1 = expf(w[203 + j]) / Z310[j];
    } else if (s >= 5 && s <= 305 && (s - 5) % 3 == 0) {
      int j = (s - 5) / 3; sr0 = 4 + 3 * j; v0 = 1.f;
    } else if (s >= 6 && s <= 306 && (s - 6) % 3 == 0) {
      int j = (s - 6) / 3; sr0 = 5 + 3 * j; v0 = 1.f;
    } else if (s >= 308 && s <= 608 && (s - 308) % 3 == 0) { // insert entry
      int i = (s - 308) / 3;
      sr0 = 3 + 3 * i;   v0 = expf(w[101 + i]) / Z3[i];
      sr1 = 310 + 3 * i; v1 = expf(1.f - w[203 + i]) / Z310[i];
    } else if (s >= 309 && s <= 609 && (s - 309) % 3 == 0) {
      int i = (s - 309) / 3; sr0 = 308 + 3 * i; v0 = 1.f;
    } else if (s >= 310 && s <= 610 && (s - 310) % 3 == 0) {
      int i = (s - 310) / 3; sr0 = 309 + 3 * i; v0 = 1.f;
    }
    ws[O_LVAL + s * 3 + 0] = v0;
    ws[O_LVAL + s * 3 + 1] = v1;
    ws[O_LVAL + s * 3 + 2] = v2;
    ((int*)ws)[O_LSRC + s * 3 + 0] = sr0;
    ((int*)ws)[O_LSRC + s * 3 + 1] = sr1;
    ((int*)ws)[O_LSRC + s * 3 + 2] = sr2;
  }
}

// ---------------- emission softmax -> E^T (unchanged) ----------------
__global__ void k_et(const float* __restrict__ ek, float* __restrict__ Et) {
  int s = blockIdx.x;
  int lane = threadIdx.x;
  float x[4];
  float m = -1e30f;
  #pragma unroll
  for (int k = 0; k < 4; ++k) {
    int c = lane + 64 * k;
    x[k] = (c < NECOL) ? ek[s * NECOL + c] : -1e30f;
    m = fmaxf(m, x[k]);
  }
  #pragma unroll
  for (int o = 32; o; o >>= 1) m = fmaxf(m, __shfl_xor(m, o, 64));
  float e[4]; float sum = 0.f;
  #pragma unroll
  for (int k = 0; k < 4; ++k) {
    int c = lane + 64 * k;
    e[k] = (c < NECOL) ? expf(x[k] - m) : 0.f;
    sum += e[k];
  }
  #pragma unroll
  for (int o = 32; o; o >>= 1) sum += __shfl_xor(sum, o, 64);
  float inv = 1.f / sum;
  #pragma unroll
  for (int k = 0; k < 4; ++k) {
    int c = lane + 64 * k;
    if (c < NECOL) Et[c * NS + s] = e[k] * inv;
  }
}

// ---------------- init softmax (unchanged) ----------------
__global__ void k_pi(const float* __restrict__ ik, float* __restrict__ pi) {
  __shared__ float wm[10], wsm[10];
  int tid = threadIdx.x;
  int lane = tid & 63, wid = tid >> 6;
  float x = (tid < NS) ? ik[tid] : -1e30f;
  float m = x;
  #pragma unroll
  for (int o = 32; o; o >>= 1) m = fmaxf(m, __shfl_xor(m, o, 64));
  if (lane == 0) wm[wid] = m;
  __syncthreads();
  float mm = wm[0];
  #pragma unroll
  for (int k = 1; k < 10; ++k) mm = fmaxf(mm, wm[k]);
  float e = (tid < NS) ? expf(x - mm) : 0.f;
  float sacc = e;
  #pragma unroll
  for (int o = 32; o; o >>= 1) sacc += __shfl_xor(sacc, o, 64);
  if (lane == 0) wsm[wid] = sacc;
  __syncthreads();
  float ss = 0.f;
  #pragma unroll
  for (int k = 0; k < 10; ++k) ss += wsm[k];
  if (tid < NS) pi[tid] = e / ss;
}

// ---------------- DPP wave64 inclusive add-scan (lane63 = wave total) --------
#define DPP_ADD(x, ctrl, rmask) \
  ((x) + __int_as_float(__builtin_amdgcn_update_dpp(0, __float_as_int(x), ctrl, rmask, 0xf, true)))

__device__ __forceinline__ float wave_scan(float x) {
  x = DPP_ADD(x, 0x111, 0xf);   // row_shr:1
  x = DPP_ADD(x, 0x112, 0xf);   // row_shr:2
  x = DPP_ADD(x, 0x114, 0xf);   // row_shr:4
  x = DPP_ADD(x, 0x118, 0xf);   // row_shr:8
  x = DPP_ADD(x, 0x142, 0xa);   // row_bcast:15 -> rows 1,3
  x = DPP_ADD(x, 0x143, 0xc);   // row_bcast:31 -> rows 2,3
  return x;
}

// ---------------- main forward scan: one block per sequence ----------------
// Single barrier per step: full double-buffering of all cross-thread state.
// Ownership: tid 0..99  -> s0 = 4+3*tid (match col j=tid), s1 = 3+3*tid (md src)
//            tid 100    -> s0 = 304
//            tid 101+   -> one of the remaining 411 states
__global__ __launch_bounds__(512) void k_main(const int* __restrict__ ids,
                                              const float* __restrict__ ws,
                                              float* __restrict__ out) {
  const float* lval  = ws + O_LVAL;
  const int*   lsrc  = (const int*)(ws + O_LSRC);
  const float* Gg    = ws + O_G;
  const float* iz3   = ws + O_IZ3;
  const int*   pWd   = (const int*)(ws + O_WD);
  const float* pi    = ws + O_PI;
  const float* Et    = ws + O_ET;

  __shared__ float alpha[2][616];
  __shared__ float mdl[2][204];    // [0..100]=0 pad, data at [101..200]
  __shared__ float Pxl[2][204];    // wave-local inclusive prefix, same layout
  __shared__ float wredl[2][8];
  __shared__ float totl[2];
  __shared__ float Gl[104];

  int tid = threadIdx.x, b = blockIdx.x;
  int lane = tid & 63, wid = tid >> 6;
  const int* idsb = ids + b * TLEN;

  // ---- ownership ----
  int s0, s1;
  if (tid <= 99)       { s0 = 4 + 3 * tid; s1 = 3 + 3 * tid; }
  else if (tid == 100) { s0 = 304; s1 = -1; }
  else {
    int r = tid - 101;
    if (r < 3)        s0 = r;
    else if (r < 103) s0 = 5 + 3 * (r - 3);
    else if (r == 103) s0 = 303;
    else               s0 = 305 + (r - 104);
    s1 = -1;
  }
  bool isMatch = (tid >= 1 && tid <= 100);

  int Wd = *pWd;
  float iz = (tid < 100) ? iz3[tid] : 0.f;

  // ---- one-time LDS setup ----
  if (tid < 101) Gl[tid] = Gg[tid];
  if (tid >= 101 && tid < 104) Gl[tid] = 0.f;
  for (int i = tid; i < 204; i += 512) {
    if (i < 101 || i > 200) {
      mdl[0][i] = 0.f; mdl[1][i] = 0.f;
      Pxl[0][i] = 0.f; Pxl[1][i] = 0.f;
    }
  }
  if (tid < 8) alpha[tid >> 2][612 + (tid & 3)] = 0.f;

  // ---- light edge tables into registers ----
  float lv0[3], lv1[3]; int ls0[3], ls1[3];
  #pragma unroll
  for (int k = 0; k < 3; ++k) {
    lv0[k] = lval[s0 * 3 + k];
    ls0[k] = lsrc[s0 * 3 + k];
    if (s1 >= 0) { lv1[k] = lval[s1 * 3 + k]; ls1[k] = lsrc[s1 * 3 + k]; }
    else         { lv1[k] = 0.f; ls1[k] = NS; }
  }

  // ---- t = 0 init: alpha = pi * Et[obs0]; produce buffer 0 ----
  int ob0 = idsb[0];
  float a0 = pi[s0] * Et[ob0 * NS + s0];
  float a1 = (s1 >= 0) ? pi[s1] * Et[ob0 * NS + s1] : 0.f;
  alpha[0][s0] = a0;
  if (s1 >= 0) alpha[0][s1] = a1;

  float mdv = (tid < 100) ? a1 * iz : 0.f;
  if (wid < 2) {
    float x = wave_scan(mdv);
    if (tid < 100) { mdl[0][101 + tid] = mdv; Pxl[0][101 + tid] = x; }
    if (tid == 63) totl[0] = x;
  }
  float pg = wave_scan(a0 + a1);
  if (lane == 63) wredl[0][wid] = pg;

  // ---- emission prefetch for t=1; ids two-ahead ----
  int ob1 = idsb[1];
  float e0 = Et[ob1 * NS + s0];
  float e1 = (s1 >= 0) ? Et[ob1 * NS + s1] : 0.f;
  int obn = idsb[2];

  double ll = 0.0;
  __syncthreads();

  int rb = 0;
  for (int t = 1; t < TLEN; ++t) {
    // issue next-step prefetches first (hidden under this step's compute)
    float en0 = Et[obn * NS + s0];
    float en1 = (s1 >= 0) ? Et[obn * NS + s1] : 0.f;
    int obn2 = idsb[t < TLEN - 2 ? t + 2 : TLEN - 1];

    // lagged normalization from last step's per-wave sums
    float ssum = ((wredl[rb][0] + wredl[rb][1]) + (wredl[rb][2] + wredl[rb][3]))
               + ((wredl[rb][4] + wredl[rb][5]) + (wredl[rb][6] + wredl[rb][7]));
    float inv = 1.f / ssum;
    ll += (double)logf(ssum);

    // sparse gather of alpha_{t-1}
    const float* ar = alpha[rb];
    float la0 = lv0[0] * ar[ls0[0]] + lv0[1] * ar[ls0[1]] + lv0[2] * ar[ls0[2]];
    float la1 = (s1 >= 0)
              ? lv1[0] * ar[ls1[0]] + lv1[1] * ar[ls1[1]] + lv1[2] * ar[ls1[2]]
              : 0.f;

    // delete-edge causal conv: short exact window + e * prefix
    float dacc = 0.f;
    if (isMatch) {
      int j = tid;
      const float* mr = mdl[rb];
      for (int d = 1; d <= Wd; ++d) dacc += mr[101 + j - d] * Gl[d];
      int kk = j - Wd - 1;
      float lead = Pxl[rb][101 + kk];
      if (kk >= 64) lead += totl[rb];
      dacc += CE * lead;
    }

    int wb = rb ^ 1;
    float na0 = (la0 + dacc) * e0 * inv;
    float na1 = la1 * e1 * inv;
    alpha[wb][s0] = na0;
    if (s1 >= 0) alpha[wb][s1] = na1;

    // md + wave-local prefix for NEXT step (from freshly computed alpha_t)
    float mdn = (tid < 100) ? na1 * iz : 0.f;
    if (wid < 2) {
      float x = wave_scan(mdn);
      if (tid < 100) { mdl[wb][101 + tid] = mdn; Pxl[wb][101 + tid] = x; }
      if (tid == 63) totl[wb] = x;
    }
    // per-wave sum of alpha_t for next step's normalization
    float pw = wave_scan(na0 + na1);
    if (lane == 63) wredl[wb][wid] = pw;

    __syncthreads();
    rb = wb;
    e0 = en0; e1 = en1; obn = obn2;
  }

  // final: ll += log(sum(alpha_final))
  float ssum = ((wredl[rb][0] + wredl[rb][1]) + (wredl[rb][2] + wredl[rb][3]))
             + ((wredl[rb][4] + wredl[rb][5]) + (wredl[rb][6] + wredl[rb][7]));
  ll += (double)logf(ssum);
  if (tid == 0) out[b] = (float)ll;
}

// ---------------- launcher ----------------
extern "C" void kernel_launch(void* const* d_in, const int* in_sizes, int n_in,
                              void* d_out, int out_size, void* d_ws, size_t ws_size,
                              hipStream_t stream) {
  const int*   ids = (const int*)d_in[0];
  const float* w   = (const float*)d_in[1];
  const float* ek  = (const float*)d_in[2];
  const float* ik  = (const float*)d_in[3];
  float* ws  = (float*)d_ws;
  float* out = (float*)d_out;

  k_prep<<<1, 512, 0, stream>>>(w, ws);
  k_pi  <<<1, 640, 0, stream>>>(ik, ws + O_PI);
  k_et  <<<NS, 64, 0, stream>>>(ek, ws + O_ET);
  k_main<<<BATCH, 512, 0, stream>>>(ids, ws, out);
}

// Round 3
// 1175.704 us; speedup vs baseline: 2.0241x; 1.3025x over previous
//
#include <hip/hip_runtime.h>
#include <math.h>

// ---------------- problem constants ----------------
#define NS 612          // states
#define NECOL 216       // emission cols
#define BATCH 32
#define TLEN 2048
#define WMAX 16         // compile-time delete-window unroll (Wd clamped to this)

// ---------------- ws layout (float offsets) ----------------
#define O_LVAL 0                    // [612*3] f32 light edge values (A after softmax)
#define O_LSRC 1836                 // [612*3] i32 light edge source states (612 = dummy)
#define O_G    3672                 // [101] f32: G[d] = exp(1 - wk^(d+1)), d=1..100
#define O_IZ3  3773                 // [101] f32: 1/Z3[j]
#define O_WD   3874                 // [1] i32: exact-window length W
#define O_PI   3875                 // [612] f32 softmax(init)
#define O_ET   4487                 // [216*612] f32 E^T (row = obs symbol, col = state)

#define CE 2.7182818284590452f

// ---------------- prep: transition-derived tables (unchanged, verified) ------
__global__ void k_prep(const float* __restrict__ w, float* __restrict__ ws) {
  __shared__ float Gs[101], Z3[101], Z310[101];
  int tid = threadIdx.x;
  float wk = w[304];

  if (tid >= 1 && tid <= 100) {
    float p = wk;
    for (int k = 0; k < tid; ++k) p *= wk;     // wk^(tid+1)
    float g = expf(1.f - p);
    Gs[tid] = g;
    ws[O_G + tid] = g;
  }
  if (tid == 0) {
    Gs[0] = 0.f; ws[O_G] = 0.f;
    float a = fabsf(wk);
    int W = 100; float p = a * a * a;
    for (int W1 = 1; W1 <= 100; ++W1) {
      if (p < 1e-8f) { W = W1; break; }
      p *= a;
    }
    ((int*)ws)[O_WD] = W;
  }
  __syncthreads();
  if (tid <= 100) {
    float z = expf(w[tid < 100 ? 1 + tid : 202]) + expf(w[101 + tid]);
    for (int d = 1; d <= 100 - tid; ++d) z += Gs[d];
    Z3[tid] = z;
    ws[O_IZ3 + tid] = 1.f / z;
    Z310[tid] = expf(w[203 + tid]) + expf(1.f - w[203 + tid]);
  }
  __syncthreads();

  for (int s = tid; s < NS; s += 512) {
    int sr0 = NS, sr1 = NS, sr2 = NS;
    float v0 = 0.f, v1 = 0.f, v2 = 0.f;
    if (s == 0) {
      float Z0 = expf(1.f - w[0]) + expf(w[0]);
      sr0 = 0; v0 = expf(1.f - w[0]) / Z0;
    } else if (s == 1) {
      float Z0 = expf(1.f - w[0]) + expf(w[0]);
      sr0 = 0; v0 = expf(w[0]) / Z0;
    } else if (s == 2) { sr0 = 1; v0 = 1.f; }
    else if (s == 3)   { sr0 = 2; v0 = 1.f; }
    else if (s == 307) { sr0 = 306; v0 = 1.f; sr1 = 307; v1 = 0.5f; }
    else if (s == 611) { sr0 = 307; v0 = 0.5f; sr1 = 611; v1 = 1.f; }
    else if (s >= 4 && s <= 306 && (s - 4) % 3 == 0) {       // match col 4+3j
      int j = (s - 4) / 3;
      sr0 = 3 + 3 * j;   v0 = expf(w[j < 100 ? 1 + j : 202]) / Z3[j];
      sr1 = 310 + 3 * j; v1 = expf(w[203 + j]) / Z310[j];
    } else if (s >= 5 && s <= 305 && (s - 5) % 3 == 0) {
      int j = (s - 5) / 3; sr0 = 4 + 3 * j; v0 = 1.f;
    } else if (s >= 6 && s <= 306 && (s - 6) % 3 == 0) {
      int j = (s - 6) / 3; sr0 = 5 + 3 * j; v0 = 1.f;
    } else if (s >= 308 && s <= 608 && (s - 308) % 3 == 0) { // insert entry
      int i = (s - 308) / 3;
      sr0 = 3 + 3 * i;   v0 = expf(w[101 + i]) / Z3[i];
      sr1 = 310 + 3 * i; v1 = expf(1.f - w[203 + i]) / Z310[i];
    } else if (s >= 309 && s <= 609 && (s - 309) % 3 == 0) {
      int i = (s - 309) / 3; sr0 = 308 + 3 * i; v0 = 1.f;
    } else if (s >= 310 && s <= 610 && (s - 310) % 3 == 0) {
      int i = (s - 310) / 3; sr0 = 309 + 3 * i; v0 = 1.f;
    }
    ws[O_LVAL + s * 3 + 0] = v0;
    ws[O_LVAL + s * 3 + 1] = v1;
    ws[O_LVAL + s * 3 + 2] = v2;
    ((int*)ws)[O_LSRC + s * 3 + 0] = sr0;
    ((int*)ws)[O_LSRC + s * 3 + 1] = sr1;
    ((int*)ws)[O_LSRC + s * 3 + 2] = sr2;
  }
}

// ---------------- emission softmax -> E^T (unchanged) ----------------
__global__ void k_et(const float* __restrict__ ek, float* __restrict__ Et) {
  int s = blockIdx.x;
  int lane = threadIdx.x;
  float x[4];
  float m = -1e30f;
  #pragma unroll
  for (int k = 0; k < 4; ++k) {
    int c = lane + 64 * k;
    x[k] = (c < NECOL) ? ek[s * NECOL + c] : -1e30f;
    m = fmaxf(m, x[k]);
  }
  #pragma unroll
  for (int o = 32; o; o >>= 1) m = fmaxf(m, __shfl_xor(m, o, 64));
  float e[4]; float sum = 0.f;
  #pragma unroll
  for (int k = 0; k < 4; ++k) {
    int c = lane + 64 * k;
    e[k] = (c < NECOL) ? expf(x[k] - m) : 0.f;
    sum += e[k];
  }
  #pragma unroll
  for (int o = 32; o; o >>= 1) sum += __shfl_xor(sum, o, 64);
  float inv = 1.f / sum;
  #pragma unroll
  for (int k = 0; k < 4; ++k) {
    int c = lane + 64 * k;
    if (c < NECOL) Et[c * NS + s] = e[k] * inv;
  }
}

// ---------------- init softmax (unchanged) ----------------
__global__ void k_pi(const float* __restrict__ ik, float* __restrict__ pi) {
  __shared__ float wm[10], wsm[10];
  int tid = threadIdx.x;
  int lane = tid & 63, wid = tid >> 6;
  float x = (tid < NS) ? ik[tid] : -1e30f;
  float m = x;
  #pragma unroll
  for (int o = 32; o; o >>= 1) m = fmaxf(m, __shfl_xor(m, o, 64));
  if (lane == 0) wm[wid] = m;
  __syncthreads();
  float mm = wm[0];
  #pragma unroll
  for (int k = 1; k < 10; ++k) mm = fmaxf(mm, wm[k]);
  float e = (tid < NS) ? expf(x - mm) : 0.f;
  float sacc = e;
  #pragma unroll
  for (int o = 32; o; o >>= 1) sacc += __shfl_xor(sacc, o, 64);
  if (lane == 0) wsm[wid] = sacc;
  __syncthreads();
  float ss = 0.f;
  #pragma unroll
  for (int k = 0; k < 10; ++k) ss += wsm[k];
  if (tid < NS) pi[tid] = e / ss;
}

// ---------------- DPP wave64 inclusive add-scan (lane63 = wave total) --------
#define DPP_ADD(x, ctrl, rmask) \
  ((x) + __int_as_float(__builtin_amdgcn_update_dpp(0, __float_as_int(x), ctrl, rmask, 0xf, true)))

__device__ __forceinline__ float wave_scan(float x) {
  x = DPP_ADD(x, 0x111, 0xf);   // row_shr:1
  x = DPP_ADD(x, 0x112, 0xf);   // row_shr:2
  x = DPP_ADD(x, 0x114, 0xf);   // row_shr:4
  x = DPP_ADD(x, 0x118, 0xf);   // row_shr:8
  x = DPP_ADD(x, 0x142, 0xa);   // row_bcast:15 -> rows 1,3
  x = DPP_ADD(x, 0x143, 0xc);   // row_bcast:31 -> rows 2,3
  return x;
}

// ---------------- main forward scan: one block per sequence ----------------
// Single barrier per step; delete window fully unrolled (WMAX taps, G in regs).
__global__ __launch_bounds__(512) void k_main(const int* __restrict__ ids,
                                              const float* __restrict__ ws,
                                              float* __restrict__ out) {
  const float* lval  = ws + O_LVAL;
  const int*   lsrc  = (const int*)(ws + O_LSRC);
  const float* Gg    = ws + O_G;
  const float* iz3   = ws + O_IZ3;
  const int*   pWd   = (const int*)(ws + O_WD);
  const float* pi    = ws + O_PI;
  const float* Et    = ws + O_ET;

  __shared__ float alpha[2][616];
  __shared__ float mdl[2][204];    // [0..100]=0 pad, data at [101..200]
  __shared__ float Pxl[2][204];    // wave-local inclusive prefix, same layout
  __shared__ alignas(16) float wredl[2][8];
  __shared__ float totl[2];

  int tid = threadIdx.x, b = blockIdx.x;
  int lane = tid & 63, wid = tid >> 6;
  const int* idsb = ids + b * TLEN;

  // ---- ownership ----
  int s0, s1;
  if (tid <= 99)       { s0 = 4 + 3 * tid; s1 = 3 + 3 * tid; }
  else if (tid == 100) { s0 = 304; s1 = -1; }
  else {
    int r = tid - 101;
    if (r < 3)        s0 = r;
    else if (r < 103) s0 = 5 + 3 * (r - 3);
    else if (r == 103) s0 = 303;
    else               s0 = 305 + (r - 104);
    s1 = -1;
  }
  bool isMatch = (tid >= 1 && tid <= 100);

  int Wd = *pWd;
  if (Wd > WMAX) Wd = WMAX;      // tail error <= |wk|^(WMAX+2) rel., << tolerance
  float iz = (tid < 100) ? iz3[tid] : 0.f;

  // delete-window taps in registers, zero-extended past Wd
  float gwr[WMAX];
  #pragma unroll
  for (int d = 1; d <= WMAX; ++d) gwr[d - 1] = (d <= Wd) ? Gg[d] : 0.f;

  // ---- one-time LDS setup ----
  for (int i = tid; i < 204; i += 512) {
    if (i < 101 || i > 200) {
      mdl[0][i] = 0.f; mdl[1][i] = 0.f;
      Pxl[0][i] = 0.f; Pxl[1][i] = 0.f;
    }
  }
  if (tid < 8) alpha[tid >> 2][612 + (tid & 3)] = 0.f;

  // ---- light edge tables into registers ----
  float lv0[3], lv1[3]; int ls0[3], ls1[3];
  #pragma unroll
  for (int k = 0; k < 3; ++k) {
    lv0[k] = lval[s0 * 3 + k];
    ls0[k] = lsrc[s0 * 3 + k];
    if (s1 >= 0) { lv1[k] = lval[s1 * 3 + k]; ls1[k] = lsrc[s1 * 3 + k]; }
    else         { lv1[k] = 0.f; ls1[k] = NS; }
  }

  // ---- t = 0 init: alpha = pi * Et[obs0]; produce buffer 0 ----
  int ob0 = idsb[0];
  float a0 = pi[s0] * Et[ob0 * NS + s0];
  float a1 = (s1 >= 0) ? pi[s1] * Et[ob0 * NS + s1] : 0.f;
  alpha[0][s0] = a0;
  if (s1 >= 0) alpha[0][s1] = a1;

  float mdv = (tid < 100) ? a1 * iz : 0.f;
  if (wid < 2) {
    float x = wave_scan(mdv);
    if (tid < 100) { mdl[0][101 + tid] = mdv; Pxl[0][101 + tid] = x; }
    if (tid == 63) totl[0] = x;
  }
  float pg = wave_scan(a0 + a1);
  if (lane == 63) wredl[0][wid] = pg;

  // ---- emission prefetch for t=1; ids two-ahead ----
  int ob1 = idsb[1];
  float e0 = Et[ob1 * NS + s0];
  float e1 = (s1 >= 0) ? Et[ob1 * NS + s1] : 0.f;
  int obn = idsb[2];

  double ll = 0.0;
  __syncthreads();

  int rb = 0;
  for (int t = 1; t < TLEN; ++t) {
    // issue next-step prefetches first (hidden under this step's compute)
    float en0 = Et[obn * NS + s0];
    float en1 = (s1 >= 0) ? Et[obn * NS + s1] : 0.f;
    int obn2 = idsb[t < TLEN - 2 ? t + 2 : TLEN - 1];

    // lagged normalization from last step's per-wave sums (two b128 reads)
    float4 wv0 = *(const float4*)&wredl[rb][0];
    float4 wv1 = *(const float4*)&wredl[rb][4];
    float ssum = ((wv0.x + wv0.y) + (wv0.z + wv0.w))
               + ((wv1.x + wv1.y) + (wv1.z + wv1.w));
    float inv = 1.f / ssum;
    ll += (double)logf(ssum);

    // sparse gather of alpha_{t-1}
    const float* ar = alpha[rb];
    float la0 = lv0[0] * ar[ls0[0]] + lv0[1] * ar[ls0[1]] + lv0[2] * ar[ls0[2]];
    float la1 = (s1 >= 0)
              ? lv1[0] * ar[ls1[0]] + lv1[1] * ar[ls1[1]] + lv1[2] * ar[ls1[2]]
              : 0.f;

    // delete-edge causal conv: fixed unrolled window (reads pipeline) + e*prefix
    float dacc = 0.f;
    if (isMatch) {
      const float* mr = &mdl[rb][101 + tid];
      float ac0 = 0.f, ac1 = 0.f, ac2 = 0.f, ac3 = 0.f;
      #pragma unroll
      for (int d = 1; d <= WMAX; d += 4) {
        ac0 = fmaf(mr[-d],     gwr[d - 1], ac0);
        ac1 = fmaf(mr[-d - 1], gwr[d],     ac1);
        ac2 = fmaf(mr[-d - 2], gwr[d + 1], ac2);
        ac3 = fmaf(mr[-d - 3], gwr[d + 2], ac3);
      }
      dacc = (ac0 + ac1) + (ac2 + ac3);
      int kk = tid - Wd - 1;
      float lead = Pxl[rb][101 + kk];
      if (kk >= 64) lead += totl[rb];
      dacc = fmaf(CE, lead, dacc);
    }

    int wb = rb ^ 1;
    float na0 = (la0 + dacc) * e0 * inv;
    float na1 = la1 * e1 * inv;
    alpha[wb][s0] = na0;
    if (s1 >= 0) alpha[wb][s1] = na1;

    // md + wave-local prefix for NEXT step (from freshly computed alpha_t)
    float mdn = (tid < 100) ? na1 * iz : 0.f;
    if (wid < 2) {
      float x = wave_scan(mdn);
      if (tid < 100) { mdl[wb][101 + tid] = mdn; Pxl[wb][101 + tid] = x; }
      if (tid == 63) totl[wb] = x;
    }
    // per-wave sum of alpha_t for next step's normalization
    float pw = wave_scan(na0 + na1);
    if (lane == 63) wredl[wb][wid] = pw;

    __syncthreads();
    rb = wb;
    e0 = en0; e1 = en1; obn = obn2;
  }

  // final: ll += log(sum(alpha_final))
  float4 wv0 = *(const float4*)&wredl[rb][0];
  float4 wv1 = *(const float4*)&wredl[rb][4];
  float ssum = ((wv0.x + wv0.y) + (wv0.z + wv0.w))
             + ((wv1.x + wv1.y) + (wv1.z + wv1.w));
  ll += (double)logf(ssum);
  if (tid == 0) out[b] = (float)ll;
}

// ---------------- launcher ----------------
extern "C" void kernel_launch(void* const* d_in, const int* in_sizes, int n_in,
                              void* d_out, int out_size, void* d_ws, size_t ws_size,
                              hipStream_t stream) {
  const int*   ids = (const int*)d_in[0];
  const float* w   = (const float*)d_in[1];
  const float* ek  = (const float*)d_in[2];
  const float* ik  = (const float*)d_in[3];
  float* ws  = (float*)d_ws;
  float* out = (float*)d_out;

  k_prep<<<1, 512, 0, stream>>>(w, ws);
  k_pi  <<<1, 640, 0, stream>>>(ik, ws + O_PI);
  k_et  <<<NS, 64, 0, stream>>>(ek, ws + O_ET);
  k_main<<<BATCH, 512, 0, stream>>>(ids, ws, out);
}

// Round 4
// 968.057 us; speedup vs baseline: 2.4583x; 1.2145x over previous
//
#include <hip/hip_runtime.h>
#include <math.h>

// ---------------- problem constants ----------------
#define NS 612
#define NECOL 216
#define BATCH 32
#define TLEN 2048
#define ROWW 896                 // permuted emission row stride (floats)
#define CE 2.7182818284590452f

// ---------------- ws layout (float offsets) ----------------
#define O_AV0 0                  // [101] match-entry coef  exp(w[1+i])/Z3[i]
#define O_AV1 128                // [101] insert-exit coef  exp(w[203+i])/Z310[i]
#define O_BV0 256                // [101] insert-entry coef exp(w[101+i])/Z3[i]
#define O_BV1 384                // [101] insert-keep coef  exp(1-w[203+i])/Z310[i]
#define O_IZ3 512                // [101] 1/Z3[i]
#define O_SC  640                // [0]=wk [1]=A00 [2]=A01
#define O_PIP 768                // [896] permuted softmax(init)
#define O_ET  2048               // [216*896] permuted E^T rows

// permuted slot for state s:
//  chunk0 lane L (i=0..63):   codon at L*8+{0,1,2}, insert at L*8+{4,5,6}
//  chunk1 lane L (i=64..100): codon at 512+L*6+{0,1,2}, insert at +{3,4,5}
//  specials {0,1,2,3,307,611} -> lanes 40..45, slot 512+lane*6
__device__ __forceinline__ int eslot(int s) {
  if (s >= 4 && s <= 306)  { int i = (s - 4) / 3,  r = (s - 4) % 3;  return i < 64 ? i * 8 + r     : 512 + (i - 64) * 6 + r; }
  if (s >= 308 && s <= 610){ int i = (s - 308) / 3, r = (s - 308) % 3; return i < 64 ? i * 8 + 4 + r : 512 + (i - 64) * 6 + 3 + r; }
  if (s <= 3)   return 512 + (40 + s) * 6;
  if (s == 307) return 512 + 44 * 6;
  return 512 + 45 * 6;   // s == 611
}

// integer power (k <= 64), branch-free-ish, uniform code
__device__ __forceinline__ float ipowf(float r, int k) {
  float res = 1.f, bse = r;
  #pragma unroll
  for (int q = 0; q < 7; ++q) { if (k & 1) res *= bse; bse *= bse; k >>= 1; }
  return res;
}

// ---------------- DPP helpers ----------------
#define DPPF(x, ctrl, rm) __int_as_float(__builtin_amdgcn_update_dpp(0, __float_as_int(x), (ctrl), (rm), 0xf, true))

__device__ __forceinline__ float scan_plain(float x) {
  x += DPPF(x, 0x111, 0xf);   // row_shr:1
  x += DPPF(x, 0x112, 0xf);   // row_shr:2
  x += DPPF(x, 0x114, 0xf);   // row_shr:4
  x += DPPF(x, 0x118, 0xf);   // row_shr:8
  x += DPPF(x, 0x142, 0xa);   // row_bcast:15 -> rows 1,3
  x += DPPF(x, 0x143, 0xc);   // row_bcast:31 -> rows 2,3
  return x;
}
// attenuated inclusive scan: I[l] = sum_{i<=l} v[i] * r^{l-i}
__device__ __forceinline__ float scan_atten(float x, float r1, float r2, float r4, float r8,
                                            float fA, float fB) {
  x = fmaf(DPPF(x, 0x111, 0xf), r1, x);
  x = fmaf(DPPF(x, 0x112, 0xf), r2, x);
  x = fmaf(DPPF(x, 0x114, 0xf), r4, x);
  x = fmaf(DPPF(x, 0x118, 0xf), r8, x);
  x = fmaf(DPPF(x, 0x142, 0xa), fA, x);   // fA[l] = r^{(l&15)+1}
  x = fmaf(DPPF(x, 0x143, 0xc), fB, x);   // fB[l] = r^{(l&31)+1}
  return x;
}
__device__ __forceinline__ float wshr1(float x) { return DPPF(x, 0x138, 0xf); } // wave_shr:1
__device__ __forceinline__ float rdl(float x, int l) {
  return __int_as_float(__builtin_amdgcn_readlane(__float_as_int(x), l));
}

// ---------------- prep: per-index coefficient tables ----------------
__global__ void k_prep(const float* __restrict__ w, float* __restrict__ ws) {
  __shared__ float Gs[101];
  int tid = threadIdx.x;                  // 128
  float wk = w[304];
  if (tid >= 1 && tid <= 100) {
    float p = wk;
    for (int k = 0; k < tid; ++k) p *= wk;      // wk^(tid+1)
    Gs[tid] = expf(1.f - p);
  }
  if (tid == 0) {
    Gs[0] = 0.f;
    ws[O_SC + 0] = wk;
    float Z0 = expf(1.f - w[0]) + expf(w[0]);
    ws[O_SC + 1] = expf(1.f - w[0]) / Z0;       // A00 (0->0)
    ws[O_SC + 2] = expf(w[0]) / Z0;             // A01 (0->1)
  }
  __syncthreads();
  if (tid <= 100) {
    float em = expf(w[tid < 100 ? 1 + tid : 202]);
    float ei = expf(w[101 + tid]);
    float z = em + ei;
    for (int d = 1; d <= 100 - tid; ++d) z += Gs[d];
    float ex = expf(w[203 + tid]);
    float es = expf(1.f - w[203 + tid]);
    float z310 = ex + es;
    ws[O_AV0 + tid] = em / z;
    ws[O_BV0 + tid] = ei / z;
    ws[O_AV1 + tid] = ex / z310;
    ws[O_BV1 + tid] = es / z310;
    ws[O_IZ3 + tid] = 1.f / z;
  }
}

// ---------------- emission softmax -> permuted E^T ----------------
__global__ void k_et(const float* __restrict__ ek, float* __restrict__ ws) {
  float* Etp = ws + O_ET;
  int s = blockIdx.x;
  int lane = threadIdx.x;                 // 64
  int sl = eslot(s);
  float x[4]; float m = -1e30f;
  #pragma unroll
  for (int k = 0; k < 4; ++k) {
    int c = lane + 64 * k;
    x[k] = (c < NECOL) ? ek[s * NECOL + c] : -1e30f;
    m = fmaxf(m, x[k]);
  }
  #pragma unroll
  for (int o = 32; o; o >>= 1) m = fmaxf(m, __shfl_xor(m, o, 64));
  float e[4]; float sum = 0.f;
  #pragma unroll
  for (int k = 0; k < 4; ++k) {
    int c = lane + 64 * k;
    e[k] = (c < NECOL) ? expf(x[k] - m) : 0.f;
    sum += e[k];
  }
  #pragma unroll
  for (int o = 32; o; o >>= 1) sum += __shfl_xor(sum, o, 64);
  float inv = 1.f / sum;
  #pragma unroll
  for (int k = 0; k < 4; ++k) {
    int c = lane + 64 * k;
    if (c < NECOL) Etp[c * ROWW + sl] = e[k] * inv;
  }
}

// ---------------- init softmax -> permuted pi ----------------
__global__ void k_pi(const float* __restrict__ ik, float* __restrict__ ws) {
  float* pip = ws + O_PIP;
  __shared__ float wm[10], wsm[10];
  int tid = threadIdx.x;                  // 640
  for (int i = tid; i < ROWW; i += 640) pip[i] = 0.f;   // clear unmapped slots
  __syncthreads();
  int lane = tid & 63, wid = tid >> 6;
  float x = (tid < NS) ? ik[tid] : -1e30f;
  float m = x;
  #pragma unroll
  for (int o = 32; o; o >>= 1) m = fmaxf(m, __shfl_xor(m, o, 64));
  if (lane == 0) wm[wid] = m;
  __syncthreads();
  float mm = wm[0];
  #pragma unroll
  for (int k = 1; k < 10; ++k) mm = fmaxf(mm, wm[k]);
  float e = (tid < NS) ? expf(x - mm) : 0.f;
  float sacc = e;
  #pragma unroll
  for (int o = 32; o; o >>= 1) sacc += __shfl_xor(sacc, o, 64);
  if (lane == 0) wsm[wid] = sacc;
  __syncthreads();
  float ss = 0.f;
  #pragma unroll
  for (int k = 0; k < 10; ++k) ss += wsm[k];
  if (tid < NS) pip[eslot(tid)] = e / ss;
}

// ---------------- main forward scan: one WAVE per sequence, no LDS ----------
__global__ __launch_bounds__(64) void k_main(const int* __restrict__ ids,
                                             const float* __restrict__ ws,
                                             float* __restrict__ out) {
  const int L = threadIdx.x, b = blockIdx.x;
  const int* idsb = ids + b * TLEN;
  const float* Etp = ws + O_ET;
  const float* pip = ws + O_PIP;

  // per-lane coefficients
  float AV0_0 = ws[O_AV0 + L], AV1_0 = ws[O_AV1 + L];
  float BV0_0 = ws[O_BV0 + L], BV1_0 = ws[O_BV1 + L];
  float iz0   = ws[O_IZ3 + L];
  int i1 = 64 + L; int i1c = i1 > 100 ? 100 : i1;
  float AV0_1 = ws[O_AV0 + i1c], AV1_1 = ws[O_AV1 + i1c];
  float BV0_1 = ws[O_BV0 + i1c], BV1_1 = ws[O_BV1 + i1c];
  float wk  = ws[O_SC + 0], A00 = ws[O_SC + 1], A01 = ws[O_SC + 2];
  float iz1 = (L <= 35) ? ws[O_IZ3 + i1] : 0.f;

  // special lanes 40..45 -> states {0,1,2,3,307,611}: new = (k0*shr1 + k1*self + ext)*Et*inv
  float k0 = 0.f, k1 = 0.f;
  if (L == 40) k1 = A00;
  else if (L == 41) k0 = A01;
  else if (L == 42 || L == 43) k0 = 1.f;
  else if (L == 44) k1 = 0.5f;               // 307: ext = a306(old), self*0.5
  else if (L == 45) { k0 = 0.5f; k1 = 1.f; } // 611: 0.5*a307 + self
  const bool isSp = (L >= 40 && L <= 45);
  const bool isC1 = (L <= 36);
  const bool isL0 = (L == 0), isL44 = (L == 44);

  // series/scan constants: D[j] = e*(E0 - wk*E1 + wk^2/2*E2), E_m = atten-prefix(r=wk^m)
  const float r1 = wk, r2 = wk * wk;
  const float hw2 = 0.5f * r2;
  const float skm = 1.f - wk + hw2;
  const float r1b = r1 * r1, r1c = r1b * r1b, r1d = r1c * r1c;
  const float r2b = r2 * r2, r2c = r2b * r2b, r2d = r2c * r2c;
  const float fA1 = ipowf(r1, (L & 15) + 1), fB1 = ipowf(r1, (L & 31) + 1), st1 = ipowf(r1, L + 1);
  const float fA2 = ipowf(r2, (L & 15) + 1), fB2 = ipowf(r2, (L & 31) + 1), st2 = ipowf(r2, L + 1);

  // ---- t = 0: alpha = pi * Et[obs0] (permuted, per-lane) ----
  int ob0 = idsb[0];
  const float* R0 = Etp + (size_t)ob0 * ROWW;
  float4 pa = *(const float4*)(pip + L * 8);
  float4 pb = *(const float4*)(pip + L * 8 + 4);
  float2 qa = *(const float2*)(pip + 512 + L * 6);
  float2 qb = *(const float2*)(pip + 512 + L * 6 + 2);
  float2 qc = *(const float2*)(pip + 512 + L * 6 + 4);
  float4 ea = *(const float4*)(R0 + L * 8);
  float4 eb = *(const float4*)(R0 + L * 8 + 4);
  float2 fa = *(const float2*)(R0 + 512 + L * 6);
  float2 fb = *(const float2*)(R0 + 512 + L * 6 + 2);
  float2 fc = *(const float2*)(R0 + 512 + L * 6 + 4);

  float c4_0 = pa.x * ea.x, c5_0 = pa.y * ea.y, c6_0 = pa.z * ea.z;
  float i8_0 = pb.x * eb.x, i9_0 = pb.y * eb.y, i10_0 = pb.z * eb.z;
  float spA  = isSp ? qa.x * fa.x : 0.f;
  float c4_1 = isC1 ? qa.x * fa.x : 0.f, c5_1 = isC1 ? qa.y * fa.y : 0.f;
  float c6_1 = isC1 ? qb.x * fb.x : 0.f, i8_1 = isC1 ? qb.y * fb.y : 0.f;
  float i9_1 = isC1 ? qc.x * fc.x : 0.f, i10_1 = isC1 ? qc.y * fc.y : 0.f;

  // reduce -> ssum (lagged normalization; stored alphas are prev-step-normalized)
  float part = ((c4_0 + c5_0) + (c6_0 + i8_0)) + (i9_0 + i10_0);
  part += ((c4_1 + c5_1) + (c6_1 + i8_1)) + (i9_1 + i10_1);
  part += spA;
  float ssum = rdl(scan_plain(part), 63);

  // md + attenuated scans for next step
  float a3v = rdl(spA, 43);
  float pm0 = wshr1(c6_0); if (isL0) pm0 = a3v;
  float md0 = pm0 * iz0;
  float pm1 = wshr1(c6_1); if (isL0) pm1 = rdl(c6_0, 63);
  float md1 = (L <= 35) ? pm1 * iz1 : 0.f;
  float I0_0 = scan_plain(md0);
  float I1_0 = scan_atten(md0, r1, r1b, r1c, r1d, fA1, fB1);
  float I2_0 = scan_atten(md0, r2, r2b, r2c, r2d, fA2, fB2);
  float I0_1 = scan_plain(md1) + rdl(I0_0, 63);
  float I1_1 = fmaf(rdl(I1_0, 63), st1, scan_atten(md1, r1, r1b, r1c, r1d, fA1, fB1));
  float I2_1 = fmaf(rdl(I2_0, 63), st2, scan_atten(md1, r2, r2b, r2c, r2d, fA2, fB2));

  // prefetch emission row for t=1; ids two ahead
  int obCur = idsb[1];
  int obA   = idsb[2];
  const float* Rn = Etp + (size_t)obCur * ROWW;
  float4 nea = *(const float4*)(Rn + L * 8);
  float4 neb = *(const float4*)(Rn + L * 8 + 4);
  float2 nfa = *(const float2*)(Rn + 512 + L * 6);
  float2 nfb = *(const float2*)(Rn + 512 + L * 6 + 2);
  float2 nfc = *(const float2*)(Rn + 512 + L * 6 + 4);

  double ll = 0.0;

  for (int t = 1; t < TLEN; ++t) {
    // consume prefetched emission; issue next prefetch
    float4 Ea = nea, Eb = neb; float2 Fa = nfa, Fb = nfb, Fc = nfc;
    const float* Rx = Etp + (size_t)obA * ROWW;
    nea = *(const float4*)(Rx + L * 8);
    neb = *(const float4*)(Rx + L * 8 + 4);
    nfa = *(const float2*)(Rx + 512 + L * 6);
    nfb = *(const float2*)(Rx + 512 + L * 6 + 2);
    nfc = *(const float2*)(Rx + 512 + L * 6 + 4);
    obA = idsb[t < TLEN - 2 ? t + 2 : TLEN - 1];

    float inv = 1.f / ssum;
    ll += (double)logf(ssum);

    // cross-lane reads of OLD state
    float sa3  = rdl(spA, 43);        // a3 (old)
    float sc6t = rdl(c6_0, 63);       // alpha[3+3*64] source
    float sext = rdl(c6_1, 36);       // a306 (old) for state 307
    float pv0 = wshr1(c6_0); if (isL0) pv0 = sa3;
    float pv1 = wshr1(c6_1); if (isL0) pv1 = sc6t;
    float pvs = wshr1(spA);
    float ext = isL44 ? sext : 0.f;

    // delete contributions (series form; exact to ~|wk|^6/6)
    float cb0 = fmaf(-wk, I1_0, I0_0); cb0 = fmaf(hw2, I2_0, cb0); cb0 = fmaf(-skm, md0, cb0);
    float D0 = CE * cb0;
    float cb1 = fmaf(-wk, I1_1, I0_1); cb1 = fmaf(hw2, I2_1, cb1); cb1 = fmaf(-skm, md1, cb1);
    float D1 = CE * cb1;

    // state updates (RHS all OLD values)
    float nc4_0 = fmaf(AV0_0, pv0, fmaf(AV1_0, i10_0, D0)) * Ea.x * inv;
    float nc5_0 = c4_0 * Ea.y * inv;
    float nc6_0 = c5_0 * Ea.z * inv;
    float ni8_0 = fmaf(BV0_0, pv0, BV1_0 * i10_0) * Eb.x * inv;
    float ni9_0 = i8_0 * Eb.y * inv;
    float ni10_0 = i9_0 * Eb.z * inv;

    float nc4_1 = fmaf(AV0_1, pv1, fmaf(AV1_1, i10_1, D1)) * Fa.x * inv;
    float nc5_1 = c4_1 * Fa.y * inv;
    float nc6_1 = c5_1 * Fb.x * inv;
    float ni8_1 = fmaf(BV0_1, pv1, BV1_1 * i10_1) * Fb.y * inv;
    float ni9_1 = i8_1 * Fc.x * inv;
    float ni10_1 = i9_1 * Fc.y * inv;

    float nsp = fmaf(k0, pvs, fmaf(k1, spA, ext)) * Fa.x * inv;

    // commit
    c4_0 = nc4_0; c5_0 = nc5_0; c6_0 = nc6_0;
    i8_0 = ni8_0; i9_0 = ni9_0; i10_0 = ni10_0;
    c4_1 = nc4_1; c5_1 = nc5_1; c6_1 = nc6_1;
    i8_1 = ni8_1; i9_1 = ni9_1; i10_1 = ni10_1;
    spA = nsp;

    // reduce new alphas (cndmask-style masks: NaN-safe for garbage lanes)
    float p0 = ((c4_0 + c5_0) + (c6_0 + i8_0)) + (i9_0 + i10_0);
    float p1 = ((c4_1 + c5_1) + (c6_1 + i8_1)) + (i9_1 + i10_1);
    float pr = p0;
    if (isC1) pr += p1;
    if (isSp) pr += spA;
    ssum = rdl(scan_plain(pr), 63);

    // md + scans for next step (from NEW alphas)
    float a3n = rdl(spA, 43);
    float pm0n = wshr1(c6_0); if (isL0) pm0n = a3n;
    md0 = pm0n * iz0;
    float pm1n = wshr1(c6_1); if (isL0) pm1n = rdl(c6_0, 63);
    md1 = (L <= 35) ? pm1n * iz1 : 0.f;
    I0_0 = scan_plain(md0);
    I1_0 = scan_atten(md0, r1, r1b, r1c, r1d, fA1, fB1);
    I2_0 = scan_atten(md0, r2, r2b, r2c, r2d, fA2, fB2);
    I0_1 = scan_plain(md1) + rdl(I0_0, 63);
    I1_1 = fmaf(rdl(I1_0, 63), st1, scan_atten(md1, r1, r1b, r1c, r1d, fA1, fB1));
    I2_1 = fmaf(rdl(I2_0, 63), st2, scan_atten(md1, r2, r2b, r2c, r2d, fA2, fB2));
  }

  ll += (double)logf(ssum);
  if (L == 0) out[b] = (float)ll;
}

// ---------------- launcher ----------------
extern "C" void kernel_launch(void* const* d_in, const int* in_sizes, int n_in,
                              void* d_out, int out_size, void* d_ws, size_t ws_size,
                              hipStream_t stream) {
  const int*   ids = (const int*)d_in[0];
  const float* w   = (const float*)d_in[1];
  const float* ek  = (const float*)d_in[2];
  const float* ik  = (const float*)d_in[3];
  float* ws  = (float*)d_ws;
  float* out = (float*)d_out;

  k_prep<<<1, 128, 0, stream>>>(w, ws);
  k_pi  <<<1, 640, 0, stream>>>(ik, ws);
  k_et  <<<NS, 64, 0, stream>>>(ek, ws);
  k_main<<<BATCH, 64, 0, stream>>>(ids, ws, out);
}

// Round 5
// 503.859 us; speedup vs baseline: 4.7230x; 1.9213x over previous
//
#include <hip/hip_runtime.h>
#include <math.h>

// ---------------- problem constants ----------------
#define NS 612
#define NECOL 216
#define BATCH 32
#define TLEN 2048
#define ROWW 896                 // permuted emission row stride (floats)
#define CE 2.7182818284590452f

// ---------------- ws layout (float offsets) ----------------
#define O_AV0 0                  // [101] match-entry coef  exp(w[1+i])/Z3[i]
#define O_AV1 128                // [101] insert-exit coef  exp(w[203+i])/Z310[i]
#define O_BV0 256                // [101] insert-entry coef exp(w[101+i])/Z3[i]
#define O_BV1 384                // [101] insert-keep coef  exp(1-w[203+i])/Z310[i]
#define O_IZ3 512                // [101] 1/Z3[i]
#define O_SC  640                // [0]=wk [1]=A00 [2]=A01
#define O_PIP 768                // [896] permuted softmax(init)
#define O_ET  2048               // [216*896] permuted E^T rows

// permuted slot for state s (see round-4 mapping, verified absmax 0)
__device__ __forceinline__ int eslot(int s) {
  if (s >= 4 && s <= 306)  { int i = (s - 4) / 3,  r = (s - 4) % 3;  return i < 64 ? i * 8 + r     : 512 + (i - 64) * 6 + r; }
  if (s >= 308 && s <= 610){ int i = (s - 308) / 3, r = (s - 308) % 3; return i < 64 ? i * 8 + 4 + r : 512 + (i - 64) * 6 + 3 + r; }
  if (s <= 3)   return 512 + (40 + s) * 6;
  if (s == 307) return 512 + 44 * 6;
  return 512 + 45 * 6;   // s == 611
}

__device__ __forceinline__ float ipowf(float r, int k) {
  float res = 1.f, bse = r;
  #pragma unroll
  for (int q = 0; q < 7; ++q) { if (k & 1) res *= bse; bse *= bse; k >>= 1; }
  return res;
}

// ---------------- DPP helpers ----------------
#define DPPF(x, ctrl, rm) __int_as_float(__builtin_amdgcn_update_dpp(0, __float_as_int(x), (ctrl), (rm), 0xf, true))

__device__ __forceinline__ float scan_plain(float x) {
  x += DPPF(x, 0x111, 0xf);
  x += DPPF(x, 0x112, 0xf);
  x += DPPF(x, 0x114, 0xf);
  x += DPPF(x, 0x118, 0xf);
  x += DPPF(x, 0x142, 0xa);
  x += DPPF(x, 0x143, 0xc);
  return x;
}
__device__ __forceinline__ float scan_atten(float x, float r1, float r2, float r4, float r8,
                                            float fA, float fB) {
  x = fmaf(DPPF(x, 0x111, 0xf), r1, x);
  x = fmaf(DPPF(x, 0x112, 0xf), r2, x);
  x = fmaf(DPPF(x, 0x114, 0xf), r4, x);
  x = fmaf(DPPF(x, 0x118, 0xf), r8, x);
  x = fmaf(DPPF(x, 0x142, 0xa), fA, x);
  x = fmaf(DPPF(x, 0x143, 0xc), fB, x);
  return x;
}
__device__ __forceinline__ float wshr1(float x) { return DPPF(x, 0x138, 0xf); }
__device__ __forceinline__ float rdl(float x, int l) {
  return __int_as_float(__builtin_amdgcn_readlane(__float_as_int(x), l));
}

// ---------------- prep kernels (unchanged, verified) ----------------
__global__ void k_prep(const float* __restrict__ w, float* __restrict__ ws) {
  __shared__ float Gs[101];
  int tid = threadIdx.x;                  // 128
  float wk = w[304];
  if (tid >= 1 && tid <= 100) {
    float p = wk;
    for (int k = 0; k < tid; ++k) p *= wk;
    Gs[tid] = expf(1.f - p);
  }
  if (tid == 0) {
    Gs[0] = 0.f;
    ws[O_SC + 0] = wk;
    float Z0 = expf(1.f - w[0]) + expf(w[0]);
    ws[O_SC + 1] = expf(1.f - w[0]) / Z0;
    ws[O_SC + 2] = expf(w[0]) / Z0;
  }
  __syncthreads();
  if (tid <= 100) {
    float em = expf(w[tid < 100 ? 1 + tid : 202]);
    float ei = expf(w[101 + tid]);
    float z = em + ei;
    for (int d = 1; d <= 100 - tid; ++d) z += Gs[d];
    float ex = expf(w[203 + tid]);
    float es = expf(1.f - w[203 + tid]);
    float z310 = ex + es;
    ws[O_AV0 + tid] = em / z;
    ws[O_BV0 + tid] = ei / z;
    ws[O_AV1 + tid] = ex / z310;
    ws[O_BV1 + tid] = es / z310;
    ws[O_IZ3 + tid] = 1.f / z;
  }
}

__global__ void k_et(const float* __restrict__ ek, float* __restrict__ ws) {
  float* Etp = ws + O_ET;
  int s = blockIdx.x;
  int lane = threadIdx.x;                 // 64
  int sl = eslot(s);
  float x[4]; float m = -1e30f;
  #pragma unroll
  for (int k = 0; k < 4; ++k) {
    int c = lane + 64 * k;
    x[k] = (c < NECOL) ? ek[s * NECOL + c] : -1e30f;
    m = fmaxf(m, x[k]);
  }
  #pragma unroll
  for (int o = 32; o; o >>= 1) m = fmaxf(m, __shfl_xor(m, o, 64));
  float e[4]; float sum = 0.f;
  #pragma unroll
  for (int k = 0; k < 4; ++k) {
    int c = lane + 64 * k;
    e[k] = (c < NECOL) ? expf(x[k] - m) : 0.f;
    sum += e[k];
  }
  #pragma unroll
  for (int o = 32; o; o >>= 1) sum += __shfl_xor(sum, o, 64);
  float inv = 1.f / sum;
  #pragma unroll
  for (int k = 0; k < 4; ++k) {
    int c = lane + 64 * k;
    if (c < NECOL) Etp[c * ROWW + sl] = e[k] * inv;
  }
}

__global__ void k_pi(const float* __restrict__ ik, float* __restrict__ ws) {
  float* pip = ws + O_PIP;
  __shared__ float wm[10], wsm[10];
  int tid = threadIdx.x;                  // 640
  for (int i = tid; i < ROWW; i += 640) pip[i] = 0.f;
  __syncthreads();
  int lane = tid & 63, wid = tid >> 6;
  float x = (tid < NS) ? ik[tid] : -1e30f;
  float m = x;
  #pragma unroll
  for (int o = 32; o; o >>= 1) m = fmaxf(m, __shfl_xor(m, o, 64));
  if (lane == 0) wm[wid] = m;
  __syncthreads();
  float mm = wm[0];
  #pragma unroll
  for (int k = 1; k < 10; ++k) mm = fmaxf(mm, wm[k]);
  float e = (tid < NS) ? expf(x - mm) : 0.f;
  float sacc = e;
  #pragma unroll
  for (int o = 32; o; o >>= 1) sacc += __shfl_xor(sacc, o, 64);
  if (lane == 0) wsm[wid] = sacc;
  __syncthreads();
  float ss = 0.f;
  #pragma unroll
  for (int k = 0; k < 10; ++k) ss += wsm[k];
  if (tid < NS) pip[eslot(tid)] = e / ss;
}

// ---------------- main forward scan: one WAVE per sequence, no LDS,
// unnormalized recursion + power-of-2 rescale every 8 steps ----------------
__global__ __launch_bounds__(64) void k_main(const int* __restrict__ ids,
                                             const float* __restrict__ ws,
                                             float* __restrict__ out) {
  const int L = threadIdx.x, b = blockIdx.x;
  const int* idsb = ids + b * TLEN;
  const float* Etp = ws + O_ET;
  const float* pip = ws + O_PIP;

  // per-lane coefficients
  float AV0_0 = ws[O_AV0 + L], AV1_0 = ws[O_AV1 + L];
  float BV0_0 = ws[O_BV0 + L], BV1_0 = ws[O_BV1 + L];
  float iz0   = ws[O_IZ3 + L];
  int i1 = 64 + L; int i1c = i1 > 100 ? 100 : i1;
  float AV0_1 = ws[O_AV0 + i1c], AV1_1 = ws[O_AV1 + i1c];
  float BV0_1 = ws[O_BV0 + i1c], BV1_1 = ws[O_BV1 + i1c];
  float wk  = ws[O_SC + 0], A00 = ws[O_SC + 1], A01 = ws[O_SC + 2];
  float iz1 = (L <= 35) ? ws[O_IZ3 + i1] : 0.f;

  // special lanes 40..45 -> states {0,1,2,3,307,611}
  float k0 = 0.f, k1 = 0.f;
  if (L == 40) k1 = A00;
  else if (L == 41) k0 = A01;
  else if (L == 42 || L == 43) k0 = 1.f;
  else if (L == 44) k1 = 0.5f;
  else if (L == 45) { k0 = 0.5f; k1 = 1.f; }
  const bool isSp = (L >= 40 && L <= 45);
  const bool isC1 = (L <= 36);
  const bool isL0 = (L == 0), isL44 = (L == 44);

  // series/scan constants: D[j] = e*(E0 - wk*E1) with i=j correction (1-wk)*md
  const float r1 = wk;
  const float sk1 = 1.f - wk;
  const float r1b = r1 * r1, r1c = r1b * r1b, r1d = r1c * r1c;
  const float fA1 = ipowf(r1, (L & 15) + 1), fB1 = ipowf(r1, (L & 31) + 1), st1 = ipowf(r1, L + 1);

  // ---- t = 0: beta = pi * Et[obs0] (unnormalized) ----
  int ob0 = __builtin_amdgcn_readfirstlane(idsb[0]);
  const float* R0 = Etp + (size_t)ob0 * ROWW;
  float4 pa = *(const float4*)(pip + L * 8);
  float4 pb = *(const float4*)(pip + L * 8 + 4);
  float2 qa = *(const float2*)(pip + 512 + L * 6);
  float2 qb = *(const float2*)(pip + 512 + L * 6 + 2);
  float2 qc = *(const float2*)(pip + 512 + L * 6 + 4);
  float4 ea = *(const float4*)(R0 + L * 8);
  float4 eb = *(const float4*)(R0 + L * 8 + 4);
  float2 fa = *(const float2*)(R0 + 512 + L * 6);
  float2 fb = *(const float2*)(R0 + 512 + L * 6 + 2);
  float2 fc = *(const float2*)(R0 + 512 + L * 6 + 4);

  float c4_0 = pa.x * ea.x, c5_0 = pa.y * ea.y, c6_0 = pa.z * ea.z;
  float i8_0 = pb.x * eb.x, i9_0 = pb.y * eb.y, i10_0 = pb.z * eb.z;
  float spA  = isSp ? qa.x * fa.x : 0.f;
  float c4_1 = isC1 ? qa.x * fa.x : 0.f, c5_1 = isC1 ? qa.y * fa.y : 0.f;
  float c6_1 = isC1 ? qb.x * fb.x : 0.f, i8_1 = isC1 ? qb.y * fb.y : 0.f;
  float i9_1 = isC1 ? qc.x * fc.x : 0.f, i10_1 = isC1 ? qc.y * fc.y : 0.f;

  // initial md + scans (feed D at t=1)
  float md0, md1, I0_0, I1_0, I0_1, I1_1;
  {
    float a3v = rdl(spA, 43);
    float pm0 = wshr1(c6_0); pm0 = isL0 ? a3v : pm0;
    md0 = pm0 * iz0;
    float pm1 = wshr1(c6_1); pm1 = isL0 ? rdl(c6_0, 63) : pm1;
    md1 = pm1 * iz1;
    I0_0 = scan_plain(md0);
    I1_0 = scan_atten(md0, r1, r1b, r1c, r1d, fA1, fB1);
    I0_1 = scan_plain(md1) + rdl(I0_0, 63);
    I1_1 = fmaf(rdl(I1_0, 63), st1, scan_atten(md1, r1, r1b, r1c, r1d, fA1, fB1));
  }

  int e_acc = 0;

#define STEP_BODY(Ea, Eb, Fa, Fb, Fc) do { \
    float sa3  = rdl(spA, 43); \
    float sc6t = rdl(c6_0, 63); \
    float sext = rdl(c6_1, 36); \
    float pv0 = wshr1(c6_0); pv0 = isL0 ? sa3 : pv0; \
    float pv1 = wshr1(c6_1); pv1 = isL0 ? sc6t : pv1; \
    float pvs = wshr1(spA); \
    float ext = isL44 ? sext : 0.f; \
    float cb0 = fmaf(-wk, I1_0, I0_0); cb0 = fmaf(-sk1, md0, cb0); \
    float D0 = CE * cb0; \
    float cb1 = fmaf(-wk, I1_1, I0_1); cb1 = fmaf(-sk1, md1, cb1); \
    float D1 = CE * cb1; \
    float nc4_0 = fmaf(AV0_0, pv0, fmaf(AV1_0, i10_0, D0)) * (Ea).x; \
    float nc5_0 = c4_0 * (Ea).y; \
    float nc6_0 = c5_0 * (Ea).z; \
    float ni8_0 = fmaf(BV0_0, pv0, BV1_0 * i10_0) * (Eb).x; \
    float ni9_0 = i8_0 * (Eb).y; \
    float ni10_0 = i9_0 * (Eb).z; \
    float nc4_1 = fmaf(AV0_1, pv1, fmaf(AV1_1, i10_1, D1)) * (Fa).x; \
    float nc5_1 = c4_1 * (Fa).y; \
    float nc6_1 = c5_1 * (Fb).x; \
    float ni8_1 = fmaf(BV0_1, pv1, BV1_1 * i10_1) * (Fb).y; \
    float ni9_1 = i8_1 * (Fc).x; \
    float ni10_1 = i9_1 * (Fc).y; \
    float nsp = fmaf(k0, pvs, fmaf(k1, spA, ext)) * (Fa).x; \
    c4_0 = nc4_0; c5_0 = nc5_0; c6_0 = nc6_0; \
    i8_0 = ni8_0; i9_0 = ni9_0; i10_0 = ni10_0; \
    c4_1 = nc4_1; c5_1 = nc5_1; c6_1 = nc6_1; \
    i8_1 = ni8_1; i9_1 = ni9_1; i10_1 = ni10_1; \
    spA = nsp; \
    float a3n = rdl(spA, 43); \
    float pm0n = wshr1(c6_0); pm0n = isL0 ? a3n : pm0n; \
    md0 = pm0n * iz0; \
    float pm1n = wshr1(c6_1); pm1n = isL0 ? rdl(c6_0, 63) : pm1n; \
    md1 = pm1n * iz1; \
    I0_0 = scan_plain(md0); \
    I1_0 = scan_atten(md0, r1, r1b, r1c, r1d, fA1, fB1); \
    I0_1 = scan_plain(md1) + rdl(I0_0, 63); \
    I1_1 = fmaf(rdl(I1_0, 63), st1, scan_atten(md1, r1, r1b, r1c, r1d, fA1, fB1)); \
  } while (0)

#define RESCALE() do { \
    float p0r = ((c4_0 + c5_0) + (c6_0 + i8_0)) + (i9_0 + i10_0); \
    float p1r = ((c4_1 + c5_1) + (c6_1 + i8_1)) + (i9_1 + i10_1); \
    float prr = p0r; \
    if (isC1) prr += p1r; \
    if (isSp) prr += spA; \
    float ssum = rdl(scan_plain(prr), 63); \
    int exq = ((__float_as_int(ssum) >> 23) & 255) - 127; \
    e_acc += exq; \
    float scq = __int_as_float((127 - exq) << 23); \
    c4_0 *= scq; c5_0 *= scq; c6_0 *= scq; i8_0 *= scq; i9_0 *= scq; i10_0 *= scq; \
    c4_1 *= scq; c5_1 *= scq; c6_1 *= scq; i8_1 *= scq; i9_1 *= scq; i10_1 *= scq; \
    spA *= scq; \
    md0 *= scq; md1 *= scq; I0_0 *= scq; I1_0 *= scq; I0_1 *= scq; I1_1 *= scq; \
  } while (0)

  // ---- prologue: steps t=1..7 with synchronous row loads ----
  for (int t = 1; t <= 7; ++t) {
    int obp = __builtin_amdgcn_readfirstlane(idsb[t]);
    const float* Rx = Etp + (size_t)obp * ROWW;
    float4 Ea = *(const float4*)(Rx + L * 8);
    float4 Eb = *(const float4*)(Rx + L * 8 + 4);
    float2 Fa = *(const float2*)(Rx + 512 + L * 6);
    float2 Fb = *(const float2*)(Rx + 512 + L * 6 + 2);
    float2 Fc = *(const float2*)(Rx + 512 + L * 6 + 4);
    STEP_BODY(Ea, Eb, Fa, Fb, Fc);
  }
  RESCALE();

  // ---- main: depth-2 ping-pong prefetch, groups of 8 with rescale ----
  float4 SAa, SAb; float2 SAc, SAd, SAe;
  float4 SBa, SBb; float2 SBc, SBd, SBe;
  {
    int o8 = __builtin_amdgcn_readfirstlane(idsb[8]);
    const float* R8 = Etp + (size_t)o8 * ROWW;
    SAa = *(const float4*)(R8 + L * 8);
    SAb = *(const float4*)(R8 + L * 8 + 4);
    SAc = *(const float2*)(R8 + 512 + L * 6);
    SAd = *(const float2*)(R8 + 512 + L * 6 + 2);
    SAe = *(const float2*)(R8 + 512 + L * 6 + 4);
    int o9 = __builtin_amdgcn_readfirstlane(idsb[9]);
    const float* R9 = Etp + (size_t)o9 * ROWW;
    SBa = *(const float4*)(R9 + L * 8);
    SBb = *(const float4*)(R9 + L * 8 + 4);
    SBc = *(const float2*)(R9 + 512 + L * 6);
    SBd = *(const float2*)(R9 + 512 + L * 6 + 2);
    SBe = *(const float2*)(R9 + 512 + L * 6 + 4);
  }
  int obA = idsb[10];
  int obB = idsb[11];
  int obC = idsb[12];

#define RELOAD(Ea, Eb, Fa, Fb, Fc) do { \
    int obsc = __builtin_amdgcn_readfirstlane(obA); \
    const float* Rx = Etp + (size_t)obsc * ROWW; \
    Ea = *(const float4*)(Rx + L * 8); \
    Eb = *(const float4*)(Rx + L * 8 + 4); \
    Fa = *(const float2*)(Rx + 512 + L * 6); \
    Fb = *(const float2*)(Rx + 512 + L * 6 + 2); \
    Fc = *(const float2*)(Rx + 512 + L * 6 + 4); \
  } while (0)

  for (int g = 0; g < 255; ++g) {
    #pragma unroll
    for (int k = 0; k < 8; ++k) {
      if ((k & 1) == 0) {
        STEP_BODY(SAa, SAb, SAc, SAd, SAe);
        RELOAD(SAa, SAb, SAc, SAd, SAe);
      } else {
        STEP_BODY(SBa, SBb, SBc, SBd, SBe);
        RELOAD(SBa, SBb, SBc, SBd, SBe);
      }
      obA = obB; obB = obC;
      int tix = 13 + 8 * g + k;           // t+5 for t = 8+8g+k
      tix = tix > TLEN - 1 ? TLEN - 1 : tix;
      obC = idsb[tix];
    }
    if (g != 254) RESCALE();
  }

  // ---- final: ll = e_acc*ln2 + log(sum beta_final) ----
  float p0r = ((c4_0 + c5_0) + (c6_0 + i8_0)) + (i9_0 + i10_0);
  float p1r = ((c4_1 + c5_1) + (c6_1 + i8_1)) + (i9_1 + i10_1);
  float prr = p0r;
  if (isC1) prr += p1r;
  if (isSp) prr += spA;
  float ssum_f = rdl(scan_plain(prr), 63);
  double ll = (double)e_acc * 0.6931471805599453 + (double)logf(ssum_f);
  if (L == 0) out[b] = (float)ll;

#undef STEP_BODY
#undef RESCALE
#undef RELOAD
}

// ---------------- launcher ----------------
extern "C" void kernel_launch(void* const* d_in, const int* in_sizes, int n_in,
                              void* d_out, int out_size, void* d_ws, size_t ws_size,
                              hipStream_t stream) {
  const int*   ids = (const int*)d_in[0];
  const float* w   = (const float*)d_in[1];
  const float* ek  = (const float*)d_in[2];
  const float* ik  = (const float*)d_in[3];
  float* ws  = (float*)d_ws;
  float* out = (float*)d_out;

  k_prep<<<1, 128, 0, stream>>>(w, ws);
  k_pi  <<<1, 640, 0, stream>>>(ik, ws);
  k_et  <<<NS, 64, 0, stream>>>(ek, ws);
  k_main<<<BATCH, 64, 0, stream>>>(ids, ws, out);
}

// Round 6
// 406.022 us; speedup vs baseline: 5.8611x; 1.2410x over previous
//
#include <hip/hip_runtime.h>
#include <math.h>

// ---------------- problem constants ----------------
#define NS 612
#define NECOL 216
#define BATCH 32
#define TLEN 2048
#define ROWW 1040                // permuted emission row stride (floats)
#define CE 2.7182818284590452f

// ---------------- ws layout (float offsets) ----------------
#define O_AV0 0                  // [101] match-entry coef  exp(w[1+i])/Z3[i]
#define O_AV1 128                // [101] insert-exit coef  exp(w[203+i])/Z310[i]
#define O_BV0 256                // [101] insert-entry coef exp(w[101+i])/Z3[i]
#define O_BV1 384                // [101] insert-keep coef  exp(1-w[203+i])/Z310[i]
#define O_IZ3 512                // [101] 1/Z3[i]
#define O_SC  640                // [0]=wk [1]=A00 [2]=A01
#define O_PIP 768                // [1040] permuted softmax(init)
#define O_ET  2048               // [216*1040] permuted E^T rows

// pair-interleaved slot map:
//  row floats [0..5]  = specials {0,1,2,3,307,611}
//  row floats [16+L*16 + 0..2]  codon i=2L   | [+4..6]  insert i=2L
//              [+8..10]          codon i=2L+1 | [+12..14] insert i=2L+1
__device__ __forceinline__ int eslot(int s) {
  if (s >= 4 && s <= 306)  { int i = (s - 4) / 3,  r = (s - 4) % 3;
    return 16 + (i >> 1) * 16 + (i & 1) * 8 + r; }
  if (s >= 308 && s <= 610){ int i = (s - 308) / 3, r = (s - 308) % 3;
    return 16 + (i >> 1) * 16 + (i & 1) * 8 + 4 + r; }
  if (s <= 3)   return s;
  if (s == 307) return 4;
  return 5;   // s == 611
}

__device__ __forceinline__ float ipowf(float r, int k) {
  float res = 1.f, bse = r;
  #pragma unroll
  for (int q = 0; q < 7; ++q) { if (k & 1) res *= bse; bse *= bse; k >>= 1; }
  return res;
}

// ---------------- DPP helpers ----------------
#define DPPF(x, ctrl, rm) __int_as_float(__builtin_amdgcn_update_dpp(0, __float_as_int(x), (ctrl), (rm), 0xf, true))

__device__ __forceinline__ float scan_plain(float x) {
  x += DPPF(x, 0x111, 0xf);
  x += DPPF(x, 0x112, 0xf);
  x += DPPF(x, 0x114, 0xf);
  x += DPPF(x, 0x118, 0xf);
  x += DPPF(x, 0x142, 0xa);
  x += DPPF(x, 0x143, 0xc);
  return x;
}
__device__ __forceinline__ float scan_atten(float x, float q1, float q2, float q4, float q8,
                                            float fA, float fB) {
  x = fmaf(DPPF(x, 0x111, 0xf), q1, x);
  x = fmaf(DPPF(x, 0x112, 0xf), q2, x);
  x = fmaf(DPPF(x, 0x114, 0xf), q4, x);
  x = fmaf(DPPF(x, 0x118, 0xf), q8, x);
  x = fmaf(DPPF(x, 0x142, 0xa), fA, x);
  x = fmaf(DPPF(x, 0x143, 0xc), fB, x);
  return x;
}
__device__ __forceinline__ float wshr1(float x) { return DPPF(x, 0x138, 0xf); }
__device__ __forceinline__ float rdl(float x, int l) {
  return __int_as_float(__builtin_amdgcn_readlane(__float_as_int(x), l));
}

// ---------------- prep: coefficient tables (math unchanged, verified) -------
__global__ void k_prep(const float* __restrict__ w, float* __restrict__ ws) {
  __shared__ float Gs[101];
  int tid = threadIdx.x;                  // 128
  float wk = w[304];
  if (tid >= 1 && tid <= 100) {
    float p = wk;
    for (int k = 0; k < tid; ++k) p *= wk;
    Gs[tid] = expf(1.f - p);
  }
  if (tid == 0) {
    Gs[0] = 0.f;
    ws[O_SC + 0] = wk;
    float Z0 = expf(1.f - w[0]) + expf(w[0]);
    ws[O_SC + 1] = expf(1.f - w[0]) / Z0;
    ws[O_SC + 2] = expf(w[0]) / Z0;
  }
  __syncthreads();
  if (tid <= 100) {
    float em = expf(w[tid < 100 ? 1 + tid : 202]);
    float ei = expf(w[101 + tid]);
    float z = em + ei;
    for (int d = 1; d <= 100 - tid; ++d) z += Gs[d];
    float ex = expf(w[203 + tid]);
    float es = expf(1.f - w[203 + tid]);
    float z310 = ex + es;
    ws[O_AV0 + tid] = em / z;
    ws[O_BV0 + tid] = ei / z;
    ws[O_AV1 + tid] = ex / z310;
    ws[O_BV1 + tid] = es / z310;
    ws[O_IZ3 + tid] = 1.f / z;
  }
}

// zero-fill all Et rows (unmapped slots must be 0 — lanes multiply them blindly)
__global__ void k_zr(float* __restrict__ ws) {
  float* row = ws + O_ET + (size_t)blockIdx.x * ROWW;
  for (int i = threadIdx.x; i < ROWW; i += 256) row[i] = 0.f;
}

__global__ void k_et(const float* __restrict__ ek, float* __restrict__ ws) {
  float* Etp = ws + O_ET;
  int s = blockIdx.x;
  int lane = threadIdx.x;                 // 64
  int sl = eslot(s);
  float x[4]; float m = -1e30f;
  #pragma unroll
  for (int k = 0; k < 4; ++k) {
    int c = lane + 64 * k;
    x[k] = (c < NECOL) ? ek[s * NECOL + c] : -1e30f;
    m = fmaxf(m, x[k]);
  }
  #pragma unroll
  for (int o = 32; o; o >>= 1) m = fmaxf(m, __shfl_xor(m, o, 64));
  float e[4]; float sum = 0.f;
  #pragma unroll
  for (int k = 0; k < 4; ++k) {
    int c = lane + 64 * k;
    e[k] = (c < NECOL) ? expf(x[k] - m) : 0.f;
    sum += e[k];
  }
  #pragma unroll
  for (int o = 32; o; o >>= 1) sum += __shfl_xor(sum, o, 64);
  float inv = 1.f / sum;
  #pragma unroll
  for (int k = 0; k < 4; ++k) {
    int c = lane + 64 * k;
    if (c < NECOL) Etp[(size_t)c * ROWW + sl] = e[k] * inv;
  }
}

__global__ void k_pi(const float* __restrict__ ik, float* __restrict__ ws) {
  float* pip = ws + O_PIP;
  __shared__ float wm[10], wsm[10];
  int tid = threadIdx.x;                  // 640
  for (int i = tid; i < ROWW; i += 640) pip[i] = 0.f;
  __syncthreads();
  int lane = tid & 63, wid = tid >> 6;
  float x = (tid < NS) ? ik[tid] : -1e30f;
  float m = x;
  #pragma unroll
  for (int o = 32; o; o >>= 1) m = fmaxf(m, __shfl_xor(m, o, 64));
  if (lane == 0) wm[wid] = m;
  __syncthreads();
  float mm = wm[0];
  #pragma unroll
  for (int k = 1; k < 10; ++k) mm = fmaxf(mm, wm[k]);
  float e = (tid < NS) ? expf(x - mm) : 0.f;
  float sacc = e;
  #pragma unroll
  for (int o = 32; o; o >>= 1) sacc += __shfl_xor(sacc, o, 64);
  if (lane == 0) wsm[wid] = sacc;
  __syncthreads();
  float ss = 0.f;
  #pragma unroll
  for (int k = 0; k < 10; ++k) ss += wsm[k];
  if (tid < NS) pip[eslot(tid)] = e / ss;
}

// ---------------- main: one WAVE per sequence, pair-interleaved, no LDS -----
__global__ __launch_bounds__(64) void k_main(const int* __restrict__ ids,
                                             const float* __restrict__ ws,
                                             float* __restrict__ out) {
  const int L = threadIdx.x, b = blockIdx.x;
  const int* idsb = ids + b * TLEN;
  const float* Etp = ws + O_ET;
  const float* pip = ws + O_PIP;

  // per-lane coefficient indices (clamped; invalid lanes neutralized by E=0)
  int ie = 2 * L;     if (ie > 100) ie = 100;
  int io = 2 * L + 1; if (io > 100) io = 100;
  float AV0e = ws[O_AV0 + ie], AV1e = ws[O_AV1 + ie];
  float BV0e = ws[O_BV0 + ie], BV1e = ws[O_BV1 + ie];
  float AV0o = ws[O_AV0 + io], AV1o = ws[O_AV1 + io];
  float BV0o = ws[O_BV0 + io], BV1o = ws[O_BV1 + io];
  float ize = (2 * L <= 99)     ? ws[O_IZ3 + 2 * L]     : 0.f;
  float izo = (2 * L + 1 <= 99) ? ws[O_IZ3 + 2 * L + 1] : 0.f;
  float wk  = ws[O_SC + 0], A00 = ws[O_SC + 1], A01 = ws[O_SC + 2];

  const bool isL0 = (L == 0);
  const float sk1 = 1.f - wk;
  const float r2 = wk * wk;                       // pair-step ratio
  const float q1 = r2, q2 = q1 * q1, q4 = q2 * q2, q8 = q4 * q4;
  const float fA = ipowf(r2, (L & 15) + 1), fB = ipowf(r2, (L & 31) + 1);

  const int loff = 16 + L * 16;

  // ---- t = 0: beta = pi * Et[obs0] ----
  int ob0 = __builtin_amdgcn_readfirstlane(idsb[0]);
  const float* R0 = Etp + (size_t)ob0 * ROWW;
  float4 pce = *(const float4*)(pip + loff);
  float4 pie = *(const float4*)(pip + loff + 4);
  float4 pco = *(const float4*)(pip + loff + 8);
  float4 pio = *(const float4*)(pip + loff + 12);
  float4 ps4 = *(const float4*)(pip + 0);
  float2 ps2 = *(const float2*)(pip + 4);
  float4 Ea = *(const float4*)(R0 + loff);
  float4 Eb = *(const float4*)(R0 + loff + 4);
  float4 Ec = *(const float4*)(R0 + loff + 8);
  float4 Ed = *(const float4*)(R0 + loff + 12);
  float4 Es4 = *(const float4*)(R0 + 0);
  float2 Es2 = *(const float2*)(R0 + 4);

  float c4e = pce.x * Ea.x, c5e = pce.y * Ea.y, c6e = pce.z * Ea.z;
  float i8e = pie.x * Eb.x, i9e = pie.y * Eb.y, i10e = pie.z * Eb.z;
  float c4o = pco.x * Ec.x, c5o = pco.y * Ec.y, c6o = pco.z * Ec.z;
  float i8o = pio.x * Ed.x, i9o = pio.y * Ed.y, i10o = pio.z * Ed.z;
  float a0 = ps4.x * Es4.x, a1 = ps4.y * Es4.y, a2 = ps4.z * Es4.z, a3 = ps4.w * Es4.w;
  float a307 = ps2.x * Es2.x, a611 = ps2.y * Es2.y;

  // initial md + scans (feed D at t=1)
  float mde, mdo, I0e, I0o, I1e, I1o;
  {
    float pme = wshr1(c6o); pme = isL0 ? a3 : pme;
    mde = pme * ize;
    mdo = c6e * izo;
    float v0 = mde + mdo;
    float S = scan_plain(v0);
    I0o = S; I0e = wshr1(S) + mde;
    float v1 = fmaf(wk, mde, mdo);
    float T = scan_atten(v1, q1, q2, q4, q8, fA, fB);
    I1o = T; I1e = fmaf(wk, wshr1(T), mde);
  }

  int e_acc = 0;

#define STEP_BODY(Ca, Cb, Cc, Cd, Cs4, Cs2) do { \
    float cbE = fmaf(-wk, I1e, I0e); cbE = fmaf(-sk1, mde, cbE); \
    float De = CE * cbE; \
    float cbO = fmaf(-wk, I1o, I0o); cbO = fmaf(-sk1, mdo, cbO); \
    float Do = CE * cbO; \
    float a306o = rdl(c6e, 50); \
    float pve = wshr1(c6o); pve = isL0 ? a3 : pve; \
    float pvo = c6e; \
    float t4e = fmaf(AV0e, pve, fmaf(AV1e, i10e, De)) * (Ca).x; \
    float t5e = c4e * (Ca).y; \
    float t6e = c5e * (Ca).z; \
    float t8e = fmaf(BV0e, pve, BV1e * i10e) * (Cb).x; \
    float t9e = i8e * (Cb).y; \
    float tXe = i9e * (Cb).z; \
    float t4o = fmaf(AV0o, pvo, fmaf(AV1o, i10o, Do)) * (Cc).x; \
    float t5o = c4o * (Cc).y; \
    float t6o = c5o * (Cc).z; \
    float t8o = fmaf(BV0o, pvo, BV1o * i10o) * (Cd).x; \
    float t9o = i8o * (Cd).y; \
    float tXo = i9o * (Cd).z; \
    float n0 = A00 * a0 * (Cs4).x; \
    float n1 = A01 * a0 * (Cs4).y; \
    float n2 = a1 * (Cs4).z; \
    float n3 = a2 * (Cs4).w; \
    float n7 = fmaf(0.5f, a307, a306o) * (Cs2).x; \
    float nB = fmaf(0.5f, a307, a611) * (Cs2).y; \
    c4e = t4e; c5e = t5e; c6e = t6e; i8e = t8e; i9e = t9e; i10e = tXe; \
    c4o = t4o; c5o = t5o; c6o = t6o; i8o = t8o; i9o = t9o; i10o = tXo; \
    a0 = n0; a1 = n1; a2 = n2; a3 = n3; a307 = n7; a611 = nB; \
    float pme = wshr1(c6o); pme = isL0 ? a3 : pme; \
    mde = pme * ize; \
    mdo = c6e * izo; \
    float v0 = mde + mdo; \
    float S = scan_plain(v0); \
    I0o = S; I0e = wshr1(S) + mde; \
    float v1 = fmaf(wk, mde, mdo); \
    float T = scan_atten(v1, q1, q2, q4, q8, fA, fB); \
    I1o = T; I1e = fmaf(wk, wshr1(T), mde); \
  } while (0)

#define RESCALE() do { \
    float prr = ((c4e + c5e) + (c6e + i8e)) + ((i9e + i10e) + (c4o + c5o)) \
              + ((c6o + i8o) + (i9o + i10o)); \
    float spsum = ((a0 + a1) + (a2 + a3)) + (a307 + a611); \
    prr += isL0 ? spsum : 0.f; \
    float ssum = rdl(scan_plain(prr), 63); \
    int exq = ((__float_as_int(ssum) >> 23) & 255) - 127; \
    e_acc += exq; \
    float scq = __int_as_float((127 - exq) << 23); \
    c4e *= scq; c5e *= scq; c6e *= scq; i8e *= scq; i9e *= scq; i10e *= scq; \
    c4o *= scq; c5o *= scq; c6o *= scq; i8o *= scq; i9o *= scq; i10o *= scq; \
    a0 *= scq; a1 *= scq; a2 *= scq; a3 *= scq; a307 *= scq; a611 *= scq; \
    mde *= scq; mdo *= scq; I0e *= scq; I0o *= scq; I1e *= scq; I1o *= scq; \
  } while (0)

  // ---- prologue: t = 1..7 synchronous ----
  for (int t = 1; t <= 7; ++t) {
    int obp = __builtin_amdgcn_readfirstlane(idsb[t]);
    const float* Rx = Etp + (size_t)obp * ROWW;
    float4 Pa = *(const float4*)(Rx + loff);
    float4 Pb = *(const float4*)(Rx + loff + 4);
    float4 Pc = *(const float4*)(Rx + loff + 8);
    float4 Pd = *(const float4*)(Rx + loff + 12);
    float4 Ps4 = *(const float4*)(Rx + 0);
    float2 Ps2 = *(const float2*)(Rx + 4);
    STEP_BODY(Pa, Pb, Pc, Pd, Ps4, Ps2);
  }
  RESCALE();

  // ---- main: depth-2 ping-pong prefetch, groups of 8 ----
  float4 SAa, SAb, SAc, SAd, SAs4; float2 SAs2;
  float4 SBa, SBb, SBc, SBd, SBs4; float2 SBs2;
  {
    int o8 = __builtin_amdgcn_readfirstlane(idsb[8]);
    const float* R8 = Etp + (size_t)o8 * ROWW;
    SAa = *(const float4*)(R8 + loff);
    SAb = *(const float4*)(R8 + loff + 4);
    SAc = *(const float4*)(R8 + loff + 8);
    SAd = *(const float4*)(R8 + loff + 12);
    SAs4 = *(const float4*)(R8 + 0);
    SAs2 = *(const float2*)(R8 + 4);
    int o9 = __builtin_amdgcn_readfirstlane(idsb[9]);
    const float* R9 = Etp + (size_t)o9 * ROWW;
    SBa = *(const float4*)(R9 + loff);
    SBb = *(const float4*)(R9 + loff + 4);
    SBc = *(const float4*)(R9 + loff + 8);
    SBd = *(const float4*)(R9 + loff + 12);
    SBs4 = *(const float4*)(R9 + 0);
    SBs2 = *(const float2*)(R9 + 4);
  }
  int obA = idsb[10];
  int obB = idsb[11];
  int obC = idsb[12];

#define RELOAD(Ta, Tb, Tc, Td, Ts4, Ts2) do { \
    int obsc = __builtin_amdgcn_readfirstlane(obA); \
    const float* Rx = Etp + (size_t)obsc * ROWW; \
    Ta = *(const float4*)(Rx + loff); \
    Tb = *(const float4*)(Rx + loff + 4); \
    Tc = *(const float4*)(Rx + loff + 8); \
    Td = *(const float4*)(Rx + loff + 12); \
    Ts4 = *(const float4*)(Rx + 0); \
    Ts2 = *(const float2*)(Rx + 4); \
  } while (0)

  for (int g = 0; g < 255; ++g) {
    #pragma unroll
    for (int k = 0; k < 8; ++k) {
      if ((k & 1) == 0) {
        STEP_BODY(SAa, SAb, SAc, SAd, SAs4, SAs2);
        RELOAD(SAa, SAb, SAc, SAd, SAs4, SAs2);
      } else {
        STEP_BODY(SBa, SBb, SBc, SBd, SBs4, SBs2);
        RELOAD(SBa, SBb, SBc, SBd, SBs4, SBs2);
      }
      obA = obB; obB = obC;
      int tix = 13 + 8 * g + k;
      tix = tix > TLEN - 1 ? TLEN - 1 : tix;
      obC = idsb[tix];
    }
    if (g != 254) RESCALE();
  }

  // ---- final: ll = e_acc*ln2 + log(sum beta_final) ----
  float prr = ((c4e + c5e) + (c6e + i8e)) + ((i9e + i10e) + (c4o + c5o))
            + ((c6o + i8o) + (i9o + i10o));
  float spsum = ((a0 + a1) + (a2 + a3)) + (a307 + a611);
  prr += isL0 ? spsum : 0.f;
  float ssum_f = rdl(scan_plain(prr), 63);
  double ll = (double)e_acc * 0.6931471805599453 + (double)logf(ssum_f);
  if (L == 0) out[b] = (float)ll;

#undef STEP_BODY
#undef RESCALE
#undef RELOAD
}

// ---------------- launcher ----------------
extern "C" void kernel_launch(void* const* d_in, const int* in_sizes, int n_in,
                              void* d_out, int out_size, void* d_ws, size_t ws_size,
                              hipStream_t stream) {
  const int*   ids = (const int*)d_in[0];
  const float* w   = (const float*)d_in[1];
  const float* ek  = (const float*)d_in[2];
  const float* ik  = (const float*)d_in[3];
  float* ws  = (float*)d_ws;
  float* out = (float*)d_out;

  k_prep<<<1, 128, 0, stream>>>(w, ws);
  k_zr  <<<NECOL, 256, 0, stream>>>(ws);
  k_pi  <<<1, 640, 0, stream>>>(ik, ws);
  k_et  <<<NS, 64, 0, stream>>>(ek, ws);
  k_main<<<BATCH, 64, 0, stream>>>(ids, ws, out);
}